// Round 4
// baseline (317.496 us; speedup 1.0000x reference)
//
#include <hip/hip_runtime.h>

// PixelVectorQuantizer: z [16,256,64,64] f32, codebook [1024,256] f32
// outputs: zq (f32) + indices (as f32 values), concatenated in d_out.
//
// prep:     codebook -> bf16 swizzled chunks + f64 norms + biased f32 norms.
// stage1:   bf16 MFMA distance GEMM (16x16x32); distances packed into u32
//           sort-keys (float-bits | code) -> 5-op top-3 tracking.
//           gap2 < MARGIN -> listA (3 candidates); gap3 < MARGIN -> listB.
// resolve3: exact f64 distance for the 3 candidates (coalesced, wave/pixel).
// fullscan: exact f64 full scan for triple-near-ties (block/pixel).

#define HWSZ 4096
#define CDIM 256
#define KCODES 1024
#define NPIX 65536
#define ZQ_ELEMS (16 * 256 * 4096)
#define MARGIN 1.0f

// ws layout (fixed part)
#define WS_CBSWZ 0          // 1024*256 bf16 chunked+swizzled: 524288 B
#define WS_CBN64 524288     // double[1024]
#define WS_CBN32 532480     // float[1024]  (= ||c||^2 + 2048)
#define WS_CNT   536576     // int cntA, int cntB
#define WS_LISTS 536592     // listA (8B/entry) then listB (4B/entry)

typedef __attribute__((ext_vector_type(8))) short bf16x8;
typedef __attribute__((ext_vector_type(4))) float f32x4;
typedef __attribute__((ext_vector_type(4))) unsigned short us4;

#define MFMA16(a, b, c) __builtin_amdgcn_mfma_f32_16x16x32_bf16(a, b, c, 0, 0, 0)

__device__ __forceinline__ unsigned short f2bf(float f) {
  unsigned u = __float_as_uint(f);
  unsigned r = u + 0x7FFFu + ((u >> 16) & 1u);   // RNE
  return (unsigned short)(r >> 16);
}

__device__ __forceinline__ void gload_lds16(const void* g, void* l) {
  __builtin_amdgcn_global_load_lds(
      (const __attribute__((address_space(1))) unsigned int*)g,
      (__attribute__((address_space(3))) unsigned int*)l, 16, 0, 0);
}

// 5-op sorted-triple insert on u32 keys (v_max_u32/v_min_u32).
__device__ __forceinline__ void ins3(unsigned& k1, unsigned& k2, unsigned& k3,
                                     unsigned k) {
  unsigned c1 = k1 > k ? k1 : k;
  k1 = k1 < k ? k1 : k;
  unsigned c2 = k2 > c1 ? k2 : c1;
  k2 = k2 < c1 ? k2 : c1;
  k3 = k3 < c2 ? k3 : c2;
}

__device__ __forceinline__ float keyf(unsigned k) {
  return __uint_as_float(k & 0xFFFFFC00u);
}

// Fused prep: 256 blocks x 256 thr. Block b handles codes 4b..4b+3
// (one wave per code). Also zeroes the atomic counters.
__global__ void vq_prep(const float* __restrict__ cb,
                        unsigned short* __restrict__ cbswz,
                        double* __restrict__ cbn64,
                        float* __restrict__ cbn32p,
                        int* __restrict__ cnt) {
  const int t = threadIdx.x;
  if (blockIdx.x == 0 && t == 0) { cnt[0] = 0; cnt[1] = 0; }
  const int code = blockIdx.x * 4 + (t >> 6);
  const int lane = t & 63;
  const int c4 = lane * 4;

  float4 v = *(const float4*)(cb + (size_t)code * CDIM + c4);
  us4 hv;
  hv.x = f2bf(v.x); hv.y = f2bf(v.y); hv.z = f2bf(v.z); hv.w = f2bf(v.w);
  unsigned r = (unsigned)(code & 63);
  unsigned off = ((r << 9) + (unsigned)(c4 << 1)) ^ ((r & 7) << 4);
  *(us4*)((char*)cbswz + (size_t)(code >> 6) * 32768 + off) = hv;

  double s = (double)v.x * v.x;
  s = fma((double)v.y, (double)v.y, s);
  s = fma((double)v.z, (double)v.z, s);
  s = fma((double)v.w, (double)v.w, s);
#pragma unroll
  for (int o = 32; o; o >>= 1) s += __shfl_xor(s, o, 64);
  if (lane == 0) {
    cbn64[code] = s;
    cbn32p[code] = (float)s + 2048.0f;
  }
}

// Stage 1: 512 blocks x 256 thr, 128 px/block (4 waves x 32 px).
// LDS: 2 x 32 KB B double-buffer only (A fragments direct from global).
__launch_bounds__(256, 4)
__global__ void vq_stage1(const float* __restrict__ z,
                          const float* __restrict__ cb,
                          const unsigned short* __restrict__ cbswz,
                          const float* __restrict__ cbn32p,
                          float* __restrict__ out_zq,
                          float* __restrict__ out_idx,
                          int* __restrict__ cnt,      // [cntA, cntB]
                          int* __restrict__ listA, int capA,
                          int* __restrict__ listB, int capB) {
  extern __shared__ char smem[];
  const int t = threadIdx.x;
  const int w = t >> 6;
  const int lane = t & 63;
  const int lg = lane >> 4;
  const int p0 = blockIdx.x * 128;
  const int b = p0 >> 12;
  const int hw0 = p0 & (HWSZ - 1);
  const float* zb = z + (size_t)b * (CDIM * HWSZ) + hw0;

  // ---- A fragments: direct global -> bf16 registers ----
  bf16x8 af[2][8];
#pragma unroll
  for (int T = 0; T < 2; ++T) {
    const float* zr = zb + (w * 32 + T * 16 + (lane & 15));
#pragma unroll
    for (int kk = 0; kk < 8; ++kk) {
      const int ch0 = kk * 32 + lg * 8;
      bf16x8 f;
#pragma unroll
      for (int j = 0; j < 8; ++j)
        f[j] = (short)f2bf(zr[(size_t)(ch0 + j) * HWSZ]);
      af[T][kk] = f;
    }
  }

  // ---- prologue: chunk 0 -> buf 0 ----
  {
    const char* gsrc = (const char*)cbswz + w * 8192;
    char* ldst = smem + w * 8192;
#pragma unroll
    for (int j = 0; j < 8; ++j)
      gload_lds16(gsrc + j * 1024 + lane * 16, ldst + j * 1024);
  }
  __syncthreads();

  unsigned k1[2][4], k2[2][4], k3[2][4];
#pragma unroll
  for (int T = 0; T < 2; ++T)
#pragma unroll
    for (int q = 0; q < 4; ++q) {
      k1[T][q] = 0xFFFFFFFFu; k2[T][q] = 0xFFFFFFFFu; k3[T][q] = 0xFFFFFFFFu;
    }

  const unsigned rsw = ((unsigned)(lane & 7)) << 4;
  const unsigned kl16 = ((unsigned)lg) << 4;
  const int lcode = lane & 15;

  for (int c = 0; c < 16; ++c) {
    const char* rbuf = smem + (c & 1) * 32768;
    if (c < 15) {
      const char* gsrc = (const char*)cbswz + (c + 1) * 32768 + w * 8192;
      char* ldst = smem + ((c + 1) & 1) * 32768 + w * 8192;
#pragma unroll
      for (int j = 0; j < 8; ++j)
        gload_lds16(gsrc + j * 1024 + lane * 16, ldst + j * 1024);
    }
#pragma unroll
    for (int cs = 0; cs < 4; ++cs) {
      const int r = cs * 16 + lcode;
      const unsigned base = ((unsigned)r << 9) + kl16;
      f32x4 acc0 = {0.f, 0.f, 0.f, 0.f};
      f32x4 acc1 = {0.f, 0.f, 0.f, 0.f};
#pragma unroll
      for (int kk = 0; kk < 8; ++kk) {
        bf16x8 bf = *(const bf16x8*)(rbuf + ((base + ((unsigned)kk << 6)) ^ rsw));
        acc0 = MFMA16(af[0][kk], bf, acc0);
        acc1 = MFMA16(af[1][kk], bf, acc1);
      }
      const unsigned code = (unsigned)(c * 64 + cs * 16 + lcode);
      const float cn = cbn32p[code];
#pragma unroll
      for (int T = 0; T < 2; ++T)
#pragma unroll
        for (int q = 0; q < 4; ++q) {
          float m = fmaf(-2.f, (T == 0) ? acc0[q] : acc1[q], cn);
          unsigned key = (__float_as_uint(m) & 0xFFFFFC00u) | code;
          ins3(k1[T][q], k2[T][q], k3[T][q], key);
        }
    }
    __syncthreads();
  }

  // ---- cross-lane top-3 merge over the 16-column group ----
#pragma unroll
  for (int mask = 1; mask <= 8; mask <<= 1) {
#pragma unroll
    for (int T = 0; T < 2; ++T)
#pragma unroll
      for (int q = 0; q < 4; ++q) {
        unsigned o1 = __shfl_xor(k1[T][q], mask, 64);
        unsigned o2 = __shfl_xor(k2[T][q], mask, 64);
        unsigned o3 = __shfl_xor(k3[T][q], mask, 64);
        ins3(k1[T][q], k2[T][q], k3[T][q], o1);
        ins3(k1[T][q], k2[T][q], k3[T][q], o2);
        ins3(k1[T][q], k2[T][q], k3[T][q], o3);
      }
  }

  int* sbest = (int*)smem;  // B buffers dead now
  if ((lane & 15) == 0) {
#pragma unroll
    for (int T = 0; T < 2; ++T)
#pragma unroll
      for (int q = 0; q < 4; ++q) {
        int row = w * 32 + T * 16 + lg * 4 + q;
        int p = p0 + row;
        int i1 = (int)(k1[T][q] & 1023u);
        sbest[row] = i1;
        out_idx[p] = (float)i1;
        float f1 = keyf(k1[T][q]);
        float g2 = keyf(k2[T][q]) - f1;
        float g3 = keyf(k3[T][q]) - f1;
        if (g3 < MARGIN) {
          int pos = atomicAdd(cnt + 1, 1);
          if (pos < capB) listB[pos] = p;
        } else if (g2 < MARGIN) {
          int pos = atomicAdd(cnt, 1);
          if (pos < capA) {
            listA[2 * pos] = p | (i1 << 16);
            listA[2 * pos + 1] = (int)(k2[T][q] & 1023u) |
                                 ((int)(k3[T][q] & 1023u) << 16);
          }
        }
      }
  }
  __syncthreads();

  // ---- zq gather: coalesced over px ----
  {
    const int px = t & 127;
    const int best = sbest[px];
    const int ch0g = (t >> 7) * 128;
    const float* crow = cb + (size_t)best * CDIM + ch0g;
    float* ob = out_zq + (size_t)b * (CDIM * HWSZ) + (size_t)ch0g * HWSZ + hw0 + px;
#pragma unroll 4
    for (int c2 = 0; c2 < 128; c2 += 4) {
      float4 v = *(const float4*)(crow + c2);
      ob[(size_t)(c2 + 0) * HWSZ] = v.x;
      ob[(size_t)(c2 + 1) * HWSZ] = v.y;
      ob[(size_t)(c2 + 2) * HWSZ] = v.z;
      ob[(size_t)(c2 + 3) * HWSZ] = v.w;
    }
  }
}

// Resolve3: exact f64 check of the 3 candidate codes. One wave per entry;
// lanes span channels (coalesced codebook reads).
__launch_bounds__(256)
__global__ void vq_resolve3(const float* __restrict__ z,
                            const float* __restrict__ cb,
                            const double* __restrict__ cbn64,
                            float* __restrict__ out_zq,
                            float* __restrict__ out_idx,
                            const int* __restrict__ cnt,
                            const int* __restrict__ listA, int capA) {
  const int lane = threadIdx.x & 63;
  const int wid = (blockIdx.x * blockDim.x + threadIdx.x) >> 6;
  const int nw = (gridDim.x * blockDim.x) >> 6;
  int n = cnt[0];
  if (n > capA) n = capA;

  for (int i = wid; i < n; i += nw) {
    const int e0 = listA[2 * i];
    const int e1 = listA[2 * i + 1];
    const int p = e0 & 0xFFFF;
    int cand[3];
    cand[0] = (e0 >> 16) & 1023;
    cand[1] = e1 & 0xFFFF;
    cand[2] = (e1 >> 16) & 1023;
    const int b = p >> 12;
    const int hw = p & (HWSZ - 1);
    const float* zb = z + (size_t)b * (CDIM * HWSZ) + hw;
    const int ch0 = lane * 4;

    double zv[4];
#pragma unroll
    for (int j = 0; j < 4; ++j) zv[j] = (double)zb[(size_t)(ch0 + j) * HWSZ];

    double d[3];
#pragma unroll
    for (int tt = 0; tt < 3; ++tt) {
      float4 cv = *(const float4*)(cb + (size_t)cand[tt] * CDIM + ch0);
      double s = zv[0] * (double)cv.x;
      s = fma(zv[1], (double)cv.y, s);
      s = fma(zv[2], (double)cv.z, s);
      s = fma(zv[3], (double)cv.w, s);
#pragma unroll
      for (int off = 32; off; off >>= 1) s += __shfl_xor(s, off, 64);
      d[tt] = fma(-2.0, s, cbn64[cand[tt]]);
    }

    double bd = d[0];
    int bi = cand[0];
#pragma unroll
    for (int tt = 1; tt < 3; ++tt) {
      bool takes = (d[tt] < bd) || (d[tt] == bd && cand[tt] < bi);
      bd = takes ? d[tt] : bd;
      bi = takes ? cand[tt] : bi;
    }

    if (lane == 0) out_idx[p] = (float)bi;
    float4 cv = *(const float4*)(cb + (size_t)bi * CDIM + ch0);
    float* ob = out_zq + (size_t)b * (CDIM * HWSZ) + hw;
    ob[(size_t)(ch0 + 0) * HWSZ] = cv.x;
    ob[(size_t)(ch0 + 1) * HWSZ] = cv.y;
    ob[(size_t)(ch0 + 2) * HWSZ] = cv.z;
    ob[(size_t)(ch0 + 3) * HWSZ] = cv.w;
  }
}

// Fullscan: exact f64 full scan for triple-near-tie pixels. One block/pixel;
// 4-thread group per code, threads span channel quarters (coalesced).
__launch_bounds__(256)
__global__ void vq_fullscan(const float* __restrict__ z,
                            const float* __restrict__ cb,
                            const double* __restrict__ cbn64,
                            float* __restrict__ out_zq,
                            float* __restrict__ out_idx,
                            const int* __restrict__ cnt,
                            const int* __restrict__ listB, int capB) {
  __shared__ double zl[256];
  __shared__ double sd[4];
  __shared__ int si[4];
  __shared__ int sfin;
  int n = cnt[1];
  if (n > capB) n = capB;
  const int t = threadIdx.x;
  const int w = t >> 6;
  const int lane = t & 63;

  for (int i = blockIdx.x; i < n; i += gridDim.x) {
    const int p = listB[i];
    const int b = p >> 12;
    const int hw = p & (HWSZ - 1);
    const float* zb = z + (size_t)b * (CDIM * HWSZ) + hw;
    zl[t] = (double)zb[(size_t)t * HWSZ];
    __syncthreads();

    const int g = t >> 2;
    const int sub = t & 3;
    const double* zq4 = zl + sub * 64;
    double bd = 1e300;
    int bi = 0;

    for (int j = 0; j < 16; ++j) {
      const int code = g + 64 * j;
      const float* crow = cb + (size_t)code * CDIM + sub * 64;
      double s = 0.0;
#pragma unroll
      for (int q4 = 0; q4 < 64; q4 += 4) {
        float4 cv = *(const float4*)(crow + q4);
        s = fma(zq4[q4 + 0], (double)cv.x, s);
        s = fma(zq4[q4 + 1], (double)cv.y, s);
        s = fma(zq4[q4 + 2], (double)cv.z, s);
        s = fma(zq4[q4 + 3], (double)cv.w, s);
      }
      s += __shfl_xor(s, 1, 64);
      s += __shfl_xor(s, 2, 64);
      double d = fma(-2.0, s, cbn64[code]);
      bool takes = (d < bd) || (d == bd && code < bi);
      bd = takes ? d : bd;
      bi = takes ? code : bi;
    }

#pragma unroll
    for (int off = 4; off <= 32; off <<= 1) {
      double od = __shfl_xor(bd, off, 64);
      int oi = __shfl_xor(bi, off, 64);
      bool takes = (od < bd) || (od == bd && oi < bi);
      bd = takes ? od : bd;
      bi = takes ? oi : bi;
    }
    if (lane == 0) { sd[w] = bd; si[w] = bi; }
    __syncthreads();
    if (t == 0) {
      double fd = sd[0];
      int fi = si[0];
#pragma unroll
      for (int k = 1; k < 4; ++k) {
        bool takes = (sd[k] < fd) || (sd[k] == fd && si[k] < fi);
        fd = takes ? sd[k] : fd;
        fi = takes ? si[k] : fi;
      }
      sfin = fi;
      out_idx[p] = (float)fi;
    }
    __syncthreads();
    const int best = sfin;
    float* ob = out_zq + (size_t)b * (CDIM * HWSZ) + hw;
    ob[(size_t)t * HWSZ] = cb[(size_t)best * CDIM + t];
    __syncthreads();
  }
}

extern "C" void kernel_launch(void* const* d_in, const int* in_sizes, int n_in,
                              void* d_out, int out_size, void* d_ws, size_t ws_size,
                              hipStream_t stream) {
  const float* z = (const float*)d_in[0];
  const float* cb = (const float*)d_in[1];
  float* out = (float*)d_out;
  float* out_zq = out;
  float* out_idx = out + ZQ_ELEMS;

  char* ws = (char*)d_ws;
  unsigned short* cbswz = (unsigned short*)(ws + WS_CBSWZ);
  double* cbn64 = (double*)(ws + WS_CBN64);
  float* cbn32p = (float*)(ws + WS_CBN32);
  int* cnt = (int*)(ws + WS_CNT);

  long long avail = (long long)ws_size - WS_LISTS;
  if (avail < 0) avail = 0;
  long long capA_ll = (avail * 2 / 3) / 8;
  if (capA_ll > NPIX) capA_ll = NPIX;
  int capA = (int)capA_ll;
  int* listA = (int*)(ws + WS_LISTS);
  int* listB = (int*)(ws + WS_LISTS + (size_t)capA * 8);
  long long capB_ll = (avail - (long long)capA * 8) / 4;
  if (capB_ll > NPIX) capB_ll = NPIX;
  if (capB_ll < 0) capB_ll = 0;
  int capB = (int)capB_ll;

  vq_prep<<<256, 256, 0, stream>>>(cb, cbswz, cbn64, cbn32p, cnt);
  vq_stage1<<<512, 256, 65536, stream>>>(z, cb, cbswz, cbn32p, out_zq, out_idx,
                                         cnt, listA, capA, listB, capB);
  vq_resolve3<<<128, 256, 0, stream>>>(z, cb, cbn64, out_zq, out_idx,
                                       cnt, listA, capA);
  vq_fullscan<<<256, 256, 0, stream>>>(z, cb, cbn64, out_zq, out_idx,
                                       cnt, listB, capB);
}

// Round 5
// 223.114 us; speedup vs baseline: 1.4230x; 1.4230x over previous
//
#include <hip/hip_runtime.h>

// PixelVectorQuantizer: z [16,256,64,64] f32, codebook [1024,256] f32
// outputs: zq (f32) + indices (as f32 values), concatenated in d_out.
//
// prep:     codebook -> (-2*c) bf16 swizzled 32-code chunks + f64 norms +
//           biased f32 norms. cnt zeroing.
// stage1:   bf16 MFMA distance GEMM (16x16x32); A-frags direct from global;
//           distances packed into u32 sort-keys (float-bits | code);
//           3-op v_med3_u32 top-3 tracking.
//           gap2 < MARGIN -> listA (3 candidates); gap3 < MARGIN -> listB.
// resolve3: exact f64 distance for the 3 candidates (coalesced, wave/pixel).
// fullscan: exact f64 full scan for triple-near-ties (block/pixel).

#define HWSZ 4096
#define CDIM 256
#define KCODES 1024
#define NPIX 65536
#define ZQ_ELEMS (16 * 256 * 4096)
#define MARGIN 1.0f

// ws layout (fixed part)
#define WS_CBSWZ 0          // 1024*256 bf16, 32 chunks of 32 codes: 524288 B
#define WS_CBN64 524288     // double[1024]
#define WS_CBN32 532480     // float[1024]  (= ||c||^2 + 2048)
#define WS_CNT   536576     // int cntA, int cntB
#define WS_LISTS 536592     // listA (8B/entry) then listB (4B/entry)

typedef __attribute__((ext_vector_type(8))) short bf16x8;
typedef __attribute__((ext_vector_type(4))) float f32x4;
typedef __attribute__((ext_vector_type(4))) unsigned short us4;

#define MFMA16(a, b, c) __builtin_amdgcn_mfma_f32_16x16x32_bf16(a, b, c, 0, 0, 0)

__device__ __forceinline__ unsigned short f2bf(float f) {
  unsigned u = __float_as_uint(f);
  unsigned r = u + 0x7FFFu + ((u >> 16) & 1u);   // RNE
  return (unsigned short)(r >> 16);
}

__device__ __forceinline__ void gload_lds16(const void* g, void* l) {
  __builtin_amdgcn_global_load_lds(
      (const __attribute__((address_space(1))) unsigned int*)g,
      (__attribute__((address_space(3))) unsigned int*)l, 16, 0, 0);
}

// 3-op sorted-triple insert on u32 keys: min + 2x v_med3_u32.
// Invariant k1<=k2<=k3. k2'=med3(old k1,k2,k), k3'=med3(old k2,k3,k).
__device__ __forceinline__ void ins3(unsigned& k1, unsigned& k2, unsigned& k3,
                                     unsigned k) {
  unsigned nk2, nk3;
  asm("v_med3_u32 %0, %1, %2, %3" : "=v"(nk2) : "v"(k1), "v"(k2), "v"(k));
  asm("v_med3_u32 %0, %1, %2, %3" : "=v"(nk3) : "v"(k2), "v"(k3), "v"(k));
  k1 = k1 < k ? k1 : k;
  k2 = nk2;
  k3 = nk3;
}

__device__ __forceinline__ float keyf(unsigned k) {
  return __uint_as_float(k & 0xFFFFFC00u);
}

// Fused prep: 256 blocks x 256 thr; block b -> codes 4b..4b+3 (wave/code).
__global__ void vq_prep(const float* __restrict__ cb,
                        unsigned short* __restrict__ cbswz,
                        double* __restrict__ cbn64,
                        float* __restrict__ cbn32p,
                        int* __restrict__ cnt) {
  const int t = threadIdx.x;
  if (blockIdx.x == 0 && t == 0) { cnt[0] = 0; cnt[1] = 0; }
  const int code = blockIdx.x * 4 + (t >> 6);
  const int lane = t & 63;
  const int c4 = lane * 4;

  float4 v = *(const float4*)(cb + (size_t)code * CDIM + c4);
  us4 hv;  // store -2*c (exact power-of-2 scale) so MFMA yields -2 z.c
  hv.x = f2bf(-2.f * v.x); hv.y = f2bf(-2.f * v.y);
  hv.z = f2bf(-2.f * v.z); hv.w = f2bf(-2.f * v.w);
  unsigned r = (unsigned)(code & 31);
  unsigned off = ((r << 9) + (unsigned)(c4 << 1)) ^ ((r & 7) << 4);
  *(us4*)((char*)cbswz + (size_t)(code >> 5) * 16384 + off) = hv;

  double s = (double)v.x * v.x;
  s = fma((double)v.y, (double)v.y, s);
  s = fma((double)v.z, (double)v.z, s);
  s = fma((double)v.w, (double)v.w, s);
#pragma unroll
  for (int o = 32; o; o >>= 1) s += __shfl_xor(s, o, 64);
  if (lane == 0) {
    cbn64[code] = s;
    cbn32p[code] = (float)s + 2048.0f;  // bias keeps keys positive
  }
}

// Stage 1: 512 blocks x 256 thr, 128 px/block (4 waves x 32 px).
// LDS: 2 x 16 KB B double-buffer (32-code chunks). A frags direct global.
__launch_bounds__(256)
__global__ void vq_stage1(const float* __restrict__ z,
                          const float* __restrict__ cb,
                          const unsigned short* __restrict__ cbswz,
                          const float* __restrict__ cbn32p,
                          float* __restrict__ out_zq,
                          float* __restrict__ out_idx,
                          int* __restrict__ cnt,      // [cntA, cntB]
                          int* __restrict__ listA, int capA,
                          int* __restrict__ listB, int capB) {
  extern __shared__ char smem[];
  const int t = threadIdx.x;
  const int w = t >> 6;
  const int lane = t & 63;
  const int lg = lane >> 4;
  const int lcode = lane & 15;
  const int p0 = blockIdx.x * 128;
  const int b = p0 >> 12;
  const int hw0 = p0 & (HWSZ - 1);
  const float* zb = z + (size_t)b * (CDIM * HWSZ) + hw0;

  // ---- prologue: chunk 0 -> buf 0 (issue before A loads) ----
  {
    const char* gsrc = (const char*)cbswz + t * 16;
    char* ldst = smem + (w * 1024 + (lane >> 2) * 64) + (lane & 3) * 16;
#pragma unroll
    for (int j = 0; j < 4; ++j)
      gload_lds16(gsrc + j * 4096, ldst + j * 4096);
  }

  // ---- A fragments: direct global -> bf16 registers ----
  bf16x8 af[2][8];
#pragma unroll
  for (int T = 0; T < 2; ++T) {
    const float* zr = zb + (w * 32 + T * 16 + lcode);
#pragma unroll
    for (int kk = 0; kk < 8; ++kk) {
      const int ch0 = kk * 32 + lg * 8;
      bf16x8 f;
#pragma unroll
      for (int j = 0; j < 8; ++j)
        f[j] = (short)f2bf(zr[(size_t)(ch0 + j) * HWSZ]);
      af[T][kk] = f;
    }
  }
  __syncthreads();

  unsigned k1[2][4], k2[2][4], k3[2][4];
#pragma unroll
  for (int T = 0; T < 2; ++T)
#pragma unroll
    for (int q = 0; q < 4; ++q) {
      k1[T][q] = 0xFFFFFFFFu; k2[T][q] = 0xFFFFFFFFu; k3[T][q] = 0xFFFFFFFFu;
    }

  const unsigned rsw = ((unsigned)(lane & 7)) << 4;
  const unsigned kl16 = ((unsigned)lg) << 4;

  for (int c = 0; c < 32; ++c) {
    const char* rbuf = smem + (c & 1) * 16384;
    if (c < 31) {
      const char* gsrc = (const char*)cbswz + (c + 1) * 16384 + t * 16;
      char* ldst = smem + ((c + 1) & 1) * 16384 +
                   (w * 1024 + (lane >> 2) * 64) + (lane & 3) * 16;
#pragma unroll
      for (int j = 0; j < 4; ++j)
        gload_lds16(gsrc + j * 4096, ldst + j * 4096);
    }
#pragma unroll
    for (int cs = 0; cs < 2; ++cs) {
      const int r = cs * 16 + lcode;
      const unsigned base = ((unsigned)r << 9) + kl16;
      f32x4 acc0 = {0.f, 0.f, 0.f, 0.f};
      f32x4 acc1 = {0.f, 0.f, 0.f, 0.f};
#pragma unroll
      for (int kk = 0; kk < 8; ++kk) {
        bf16x8 bf = *(const bf16x8*)(rbuf + ((base + ((unsigned)kk << 6)) ^ rsw));
        acc0 = MFMA16(af[0][kk], bf, acc0);
        acc1 = MFMA16(af[1][kk], bf, acc1);
      }
      const unsigned code = (unsigned)(c * 32 + cs * 16 + lcode);
      const float cn = cbn32p[code];
#pragma unroll
      for (int T = 0; T < 2; ++T)
#pragma unroll
        for (int q = 0; q < 4; ++q) {
          float m = cn + ((T == 0) ? acc0[q] : acc1[q]);  // acc = -2 z.c
          unsigned key = (__float_as_uint(m) & 0xFFFFFC00u) | code;
          ins3(k1[T][q], k2[T][q], k3[T][q], key);
        }
    }
    __syncthreads();
  }

  // ---- cross-lane top-3 merge over the 16-column group ----
#pragma unroll
  for (int mask = 1; mask <= 8; mask <<= 1) {
#pragma unroll
    for (int T = 0; T < 2; ++T)
#pragma unroll
      for (int q = 0; q < 4; ++q) {
        unsigned o1 = __shfl_xor(k1[T][q], mask, 64);
        unsigned o2 = __shfl_xor(k2[T][q], mask, 64);
        unsigned o3 = __shfl_xor(k3[T][q], mask, 64);
        ins3(k1[T][q], k2[T][q], k3[T][q], o1);
        ins3(k1[T][q], k2[T][q], k3[T][q], o2);
        ins3(k1[T][q], k2[T][q], k3[T][q], o3);
      }
  }

  int* sbest = (int*)smem;  // B buffers dead now
  if (lcode == 0) {
#pragma unroll
    for (int T = 0; T < 2; ++T)
#pragma unroll
      for (int q = 0; q < 4; ++q) {
        int row = w * 32 + T * 16 + lg * 4 + q;
        int p = p0 + row;
        int i1 = (int)(k1[T][q] & 1023u);
        sbest[row] = i1;
        out_idx[p] = (float)i1;
        float f1 = keyf(k1[T][q]);
        float g2 = keyf(k2[T][q]) - f1;
        float g3 = keyf(k3[T][q]) - f1;
        if (g3 < MARGIN) {
          int pos = atomicAdd(cnt + 1, 1);
          if (pos < capB) listB[pos] = p;
        } else if (g2 < MARGIN) {
          int pos = atomicAdd(cnt, 1);
          if (pos < capA) {
            listA[2 * pos] = p | (i1 << 16);
            listA[2 * pos + 1] = (int)(k2[T][q] & 1023u) |
                                 ((int)(k3[T][q] & 1023u) << 16);
          }
        }
      }
  }
  __syncthreads();

  // ---- zq gather: coalesced over px ----
  {
    const int px = t & 127;
    const int best = sbest[px];
    const int ch0g = (t >> 7) * 128;
    const float* crow = cb + (size_t)best * CDIM + ch0g;
    float* ob = out_zq + (size_t)b * (CDIM * HWSZ) + (size_t)ch0g * HWSZ + hw0 + px;
#pragma unroll 4
    for (int c2 = 0; c2 < 128; c2 += 4) {
      float4 v = *(const float4*)(crow + c2);
      ob[(size_t)(c2 + 0) * HWSZ] = v.x;
      ob[(size_t)(c2 + 1) * HWSZ] = v.y;
      ob[(size_t)(c2 + 2) * HWSZ] = v.z;
      ob[(size_t)(c2 + 3) * HWSZ] = v.w;
    }
  }
}

// Resolve3: exact f64 check of the 3 candidate codes. One wave per entry.
__launch_bounds__(256)
__global__ void vq_resolve3(const float* __restrict__ z,
                            const float* __restrict__ cb,
                            const double* __restrict__ cbn64,
                            float* __restrict__ out_zq,
                            float* __restrict__ out_idx,
                            const int* __restrict__ cnt,
                            const int* __restrict__ listA, int capA) {
  const int lane = threadIdx.x & 63;
  const int wid = (blockIdx.x * blockDim.x + threadIdx.x) >> 6;
  const int nw = (gridDim.x * blockDim.x) >> 6;
  int n = cnt[0];
  if (n > capA) n = capA;

  for (int i = wid; i < n; i += nw) {
    const int e0 = listA[2 * i];
    const int e1 = listA[2 * i + 1];
    const int p = e0 & 0xFFFF;
    int cand[3];
    cand[0] = (e0 >> 16) & 1023;
    cand[1] = e1 & 0xFFFF;
    cand[2] = (e1 >> 16) & 1023;
    const int b = p >> 12;
    const int hw = p & (HWSZ - 1);
    const float* zb = z + (size_t)b * (CDIM * HWSZ) + hw;
    const int ch0 = lane * 4;

    double zv[4];
#pragma unroll
    for (int j = 0; j < 4; ++j) zv[j] = (double)zb[(size_t)(ch0 + j) * HWSZ];

    double d[3];
#pragma unroll
    for (int tt = 0; tt < 3; ++tt) {
      float4 cv = *(const float4*)(cb + (size_t)cand[tt] * CDIM + ch0);
      double s = zv[0] * (double)cv.x;
      s = fma(zv[1], (double)cv.y, s);
      s = fma(zv[2], (double)cv.z, s);
      s = fma(zv[3], (double)cv.w, s);
#pragma unroll
      for (int off = 32; off; off >>= 1) s += __shfl_xor(s, off, 64);
      d[tt] = fma(-2.0, s, cbn64[cand[tt]]);
    }

    double bd = d[0];
    int bi = cand[0];
#pragma unroll
    for (int tt = 1; tt < 3; ++tt) {
      bool takes = (d[tt] < bd) || (d[tt] == bd && cand[tt] < bi);
      bd = takes ? d[tt] : bd;
      bi = takes ? cand[tt] : bi;
    }

    if (lane == 0) out_idx[p] = (float)bi;
    float4 cv = *(const float4*)(cb + (size_t)bi * CDIM + ch0);
    float* ob = out_zq + (size_t)b * (CDIM * HWSZ) + hw;
    ob[(size_t)(ch0 + 0) * HWSZ] = cv.x;
    ob[(size_t)(ch0 + 1) * HWSZ] = cv.y;
    ob[(size_t)(ch0 + 2) * HWSZ] = cv.z;
    ob[(size_t)(ch0 + 3) * HWSZ] = cv.w;
  }
}

// Fullscan: exact f64 full scan for triple-near-tie pixels. One block/pixel.
__launch_bounds__(256)
__global__ void vq_fullscan(const float* __restrict__ z,
                            const float* __restrict__ cb,
                            const double* __restrict__ cbn64,
                            float* __restrict__ out_zq,
                            float* __restrict__ out_idx,
                            const int* __restrict__ cnt,
                            const int* __restrict__ listB, int capB) {
  __shared__ double zl[256];
  __shared__ double sd[4];
  __shared__ int si[4];
  __shared__ int sfin;
  int n = cnt[1];
  if (n > capB) n = capB;
  const int t = threadIdx.x;
  const int w = t >> 6;
  const int lane = t & 63;

  for (int i = blockIdx.x; i < n; i += gridDim.x) {
    const int p = listB[i];
    const int b = p >> 12;
    const int hw = p & (HWSZ - 1);
    const float* zb = z + (size_t)b * (CDIM * HWSZ) + hw;
    zl[t] = (double)zb[(size_t)t * HWSZ];
    __syncthreads();

    const int g = t >> 2;
    const int sub = t & 3;
    const double* zq4 = zl + sub * 64;
    double bd = 1e300;
    int bi = 0;

    for (int j = 0; j < 16; ++j) {
      const int code = g + 64 * j;
      const float* crow = cb + (size_t)code * CDIM + sub * 64;
      double s = 0.0;
#pragma unroll
      for (int q4 = 0; q4 < 64; q4 += 4) {
        float4 cv = *(const float4*)(crow + q4);
        s = fma(zq4[q4 + 0], (double)cv.x, s);
        s = fma(zq4[q4 + 1], (double)cv.y, s);
        s = fma(zq4[q4 + 2], (double)cv.z, s);
        s = fma(zq4[q4 + 3], (double)cv.w, s);
      }
      s += __shfl_xor(s, 1, 64);
      s += __shfl_xor(s, 2, 64);
      double d = fma(-2.0, s, cbn64[code]);
      bool takes = (d < bd) || (d == bd && code < bi);
      bd = takes ? d : bd;
      bi = takes ? code : bi;
    }

#pragma unroll
    for (int off = 4; off <= 32; off <<= 1) {
      double od = __shfl_xor(bd, off, 64);
      int oi = __shfl_xor(bi, off, 64);
      bool takes = (od < bd) || (od == bd && oi < bi);
      bd = takes ? od : bd;
      bi = takes ? oi : bi;
    }
    if (lane == 0) { sd[w] = bd; si[w] = bi; }
    __syncthreads();
    if (t == 0) {
      double fd = sd[0];
      int fi = si[0];
#pragma unroll
      for (int k = 1; k < 4; ++k) {
        bool takes = (sd[k] < fd) || (sd[k] == fd && si[k] < fi);
        fd = takes ? sd[k] : fd;
        fi = takes ? si[k] : fi;
      }
      sfin = fi;
      out_idx[p] = (float)fi;
    }
    __syncthreads();
    const int best = sfin;
    float* ob = out_zq + (size_t)b * (CDIM * HWSZ) + hw;
    ob[(size_t)t * HWSZ] = cb[(size_t)best * CDIM + t];
    __syncthreads();
  }
}

extern "C" void kernel_launch(void* const* d_in, const int* in_sizes, int n_in,
                              void* d_out, int out_size, void* d_ws, size_t ws_size,
                              hipStream_t stream) {
  const float* z = (const float*)d_in[0];
  const float* cb = (const float*)d_in[1];
  float* out = (float*)d_out;
  float* out_zq = out;
  float* out_idx = out + ZQ_ELEMS;

  char* ws = (char*)d_ws;
  unsigned short* cbswz = (unsigned short*)(ws + WS_CBSWZ);
  double* cbn64 = (double*)(ws + WS_CBN64);
  float* cbn32p = (float*)(ws + WS_CBN32);
  int* cnt = (int*)(ws + WS_CNT);

  long long avail = (long long)ws_size - WS_LISTS;
  if (avail < 0) avail = 0;
  long long capA_ll = (avail * 2 / 3) / 8;
  if (capA_ll > NPIX) capA_ll = NPIX;
  int capA = (int)capA_ll;
  int* listA = (int*)(ws + WS_LISTS);
  int* listB = (int*)(ws + WS_LISTS + (size_t)capA * 8);
  long long capB_ll = (avail - (long long)capA * 8) / 4;
  if (capB_ll > NPIX) capB_ll = NPIX;
  if (capB_ll < 0) capB_ll = 0;
  int capB = (int)capB_ll;

  vq_prep<<<256, 256, 0, stream>>>(cb, cbswz, cbn64, cbn32p, cnt);
  vq_stage1<<<512, 256, 32768, stream>>>(z, cb, cbswz, cbn32p, out_zq, out_idx,
                                         cnt, listA, capA, listB, capB);
  vq_resolve3<<<256, 256, 0, stream>>>(z, cb, cbn64, out_zq, out_idx,
                                       cnt, listA, capA);
  vq_fullscan<<<256, 256, 0, stream>>>(z, cb, cbn64, out_zq, out_idx,
                                       cnt, listB, capB);
}

// Round 6
// 187.221 us; speedup vs baseline: 1.6958x; 1.1917x over previous
//
#include <hip/hip_runtime.h>

// PixelVectorQuantizer: z [16,256,64,64] f32, codebook [1024,256] f32
// outputs: zq (f32) + indices (as f32 values), concatenated in d_out.
//
// prep:     codebook -> (-2*c) bf16 swizzled 32-code chunks + f64 norms +
//           biased f32 norms (bias 512). cnt zeroing.
// stage1:   bf16 MFMA distance GEMM (16x16x32), 16 px/wave (grid 1024 ->
//           4 waves/SIMD); u32 sort-keys (float-bits | code), 3-op
//           v_med3_u32 top-3. gap2 < MARGIN -> listA (+ f32 z-row dump to
//           ws from L2-hot lines); gap3 < MARGIN -> listB.
// resolve3: exact f64 distance for 3 candidates, z from staged rows.
// fullscan: exact f64 full scan for triple-near-ties (block/pixel).

#define HWSZ 4096
#define CDIM 256
#define KCODES 1024
#define NPIX 65536
#define ZQ_ELEMS (16 * 256 * 4096)
#define MARGIN 0.75f

// ws layout (fixed part)
#define WS_CBSWZ 0          // 1024*256 bf16, 32 chunks of 32 codes: 524288 B
#define WS_CBN64 524288     // double[1024]
#define WS_CBN32 532480     // float[1024]  (= ||c||^2 + 512)
#define WS_CNT   536576     // int cntA, int cntB
#define WS_LISTS 536592     // listA (8B) | listB (4B) | zws (1KB rows)

typedef __attribute__((ext_vector_type(8))) short bf16x8;
typedef __attribute__((ext_vector_type(4))) float f32x4;
typedef __attribute__((ext_vector_type(4))) unsigned short us4;

#define MFMA16(a, b, c) __builtin_amdgcn_mfma_f32_16x16x32_bf16(a, b, c, 0, 0, 0)

__device__ __forceinline__ unsigned short f2bf(float f) {
  unsigned u = __float_as_uint(f);
  unsigned r = u + 0x7FFFu + ((u >> 16) & 1u);   // RNE
  return (unsigned short)(r >> 16);
}

__device__ __forceinline__ void gload_lds16(const void* g, void* l) {
  __builtin_amdgcn_global_load_lds(
      (const __attribute__((address_space(1))) unsigned int*)g,
      (__attribute__((address_space(3))) unsigned int*)l, 16, 0, 0);
}

// 3-op sorted-triple insert on u32 keys: min + 2x v_med3_u32.
__device__ __forceinline__ void ins3(unsigned& k1, unsigned& k2, unsigned& k3,
                                     unsigned k) {
  unsigned nk2, nk3;
  asm("v_med3_u32 %0, %1, %2, %3" : "=v"(nk2) : "v"(k1), "v"(k2), "v"(k));
  asm("v_med3_u32 %0, %1, %2, %3" : "=v"(nk3) : "v"(k2), "v"(k3), "v"(k));
  k1 = k1 < k ? k1 : k;
  k2 = nk2;
  k3 = nk3;
}

__device__ __forceinline__ float keyf(unsigned k) {
  return __uint_as_float(k & 0xFFFFFC00u);
}

// Fused prep: 256 blocks x 256 thr; block b -> codes 4b..4b+3 (wave/code).
__global__ void vq_prep(const float* __restrict__ cb,
                        unsigned short* __restrict__ cbswz,
                        double* __restrict__ cbn64,
                        float* __restrict__ cbn32p,
                        int* __restrict__ cnt) {
  const int t = threadIdx.x;
  if (blockIdx.x == 0 && t == 0) { cnt[0] = 0; cnt[1] = 0; }
  const int code = blockIdx.x * 4 + (t >> 6);
  const int lane = t & 63;
  const int c4 = lane * 4;

  float4 v = *(const float4*)(cb + (size_t)code * CDIM + c4);
  us4 hv;  // store -2*c (exact power-of-2 scale) so MFMA yields -2 z.c
  hv.x = f2bf(-2.f * v.x); hv.y = f2bf(-2.f * v.y);
  hv.z = f2bf(-2.f * v.z); hv.w = f2bf(-2.f * v.w);
  unsigned r = (unsigned)(code & 31);
  unsigned off = ((r << 9) + (unsigned)(c4 << 1)) ^ ((r & 7) << 4);
  *(us4*)((char*)cbswz + (size_t)(code >> 5) * 16384 + off) = hv;

  double s = (double)v.x * v.x;
  s = fma((double)v.y, (double)v.y, s);
  s = fma((double)v.z, (double)v.z, s);
  s = fma((double)v.w, (double)v.w, s);
#pragma unroll
  for (int o = 32; o; o >>= 1) s += __shfl_xor(s, o, 64);
  if (lane == 0) {
    cbn64[code] = s;
    cbn32p[code] = (float)s + 512.0f;  // small bias: keys positive, quant<=0.125
  }
}

// Stage 1: 1024 blocks x 256 thr, 64 px/block (4 waves x 16 px).
// LDS: 2 x 16 KB B double-buffer (32-code chunks). A frags direct global.
__launch_bounds__(256)
__global__ void vq_stage1(const float* __restrict__ z,
                          const float* __restrict__ cb,
                          const unsigned short* __restrict__ cbswz,
                          const float* __restrict__ cbn32p,
                          float* __restrict__ out_zq,
                          float* __restrict__ out_idx,
                          int* __restrict__ cnt,      // [cntA, cntB]
                          int* __restrict__ listA, int capA,
                          int* __restrict__ listB, int capB,
                          float* __restrict__ zws, int zcap) {
  extern __shared__ char smem[];
  const int t = threadIdx.x;
  const int w = t >> 6;
  const int lane = t & 63;
  const int lg = lane >> 4;
  const int lcode = lane & 15;
  const int p0 = blockIdx.x * 64;
  const int b = p0 >> 12;
  const int hw0 = p0 & (HWSZ - 1);
  const float* zb = z + (size_t)b * (CDIM * HWSZ) + hw0;

  // ---- prologue: chunk 0 -> buf 0 (issue before A loads) ----
  {
    const char* gsrc = (const char*)cbswz + t * 16;
    char* ldst = smem + (w * 1024 + (lane >> 2) * 64) + (lane & 3) * 16;
#pragma unroll
    for (int j = 0; j < 4; ++j)
      gload_lds16(gsrc + j * 4096, ldst + j * 4096);
  }

  // ---- A fragments (16 px x 256 ch per wave): direct global -> regs ----
  bf16x8 af[8];
  {
    const float* zr = zb + (w * 16 + lcode);
#pragma unroll
    for (int kk = 0; kk < 8; ++kk) {
      const int ch0 = kk * 32 + lg * 8;
      bf16x8 f;
#pragma unroll
      for (int j = 0; j < 8; ++j)
        f[j] = (short)f2bf(zr[(size_t)(ch0 + j) * HWSZ]);
      af[kk] = f;
    }
  }
  __syncthreads();

  unsigned k1[4], k2[4], k3[4];
#pragma unroll
  for (int q = 0; q < 4; ++q) {
    k1[q] = 0xFFFFFFFFu; k2[q] = 0xFFFFFFFFu; k3[q] = 0xFFFFFFFFu;
  }

  const unsigned rsw = ((unsigned)(lane & 7)) << 4;
  const unsigned kl16 = ((unsigned)lg) << 4;

  for (int c = 0; c < 32; ++c) {
    const char* rbuf = smem + (c & 1) * 16384;
    if (c < 31) {
      const char* gsrc = (const char*)cbswz + (c + 1) * 16384 + t * 16;
      char* ldst = smem + ((c + 1) & 1) * 16384 +
                   (w * 1024 + (lane >> 2) * 64) + (lane & 3) * 16;
#pragma unroll
      for (int j = 0; j < 4; ++j)
        gload_lds16(gsrc + j * 4096, ldst + j * 4096);
    }
#pragma unroll
    for (int cs = 0; cs < 2; ++cs) {
      const int r = cs * 16 + lcode;
      const unsigned base = ((unsigned)r << 9) + kl16;
      f32x4 acc = {0.f, 0.f, 0.f, 0.f};
#pragma unroll
      for (int kk = 0; kk < 8; ++kk) {
        bf16x8 bf = *(const bf16x8*)(rbuf + ((base + ((unsigned)kk << 6)) ^ rsw));
        acc = MFMA16(af[kk], bf, acc);
      }
      const unsigned code = (unsigned)(c * 32 + cs * 16 + lcode);
      const float cn = cbn32p[code];
#pragma unroll
      for (int q = 0; q < 4; ++q) {
        float m = cn + acc[q];  // acc = -2 z.c
        unsigned key = (__float_as_uint(m) & 0xFFFFFC00u) | code;
        ins3(k1[q], k2[q], k3[q], key);
      }
    }
    __syncthreads();
  }

  // ---- cross-lane top-3 merge over the 16-column group ----
#pragma unroll
  for (int mask = 1; mask <= 8; mask <<= 1) {
#pragma unroll
    for (int q = 0; q < 4; ++q) {
      unsigned o1 = __shfl_xor(k1[q], mask, 64);
      unsigned o2 = __shfl_xor(k2[q], mask, 64);
      unsigned o3 = __shfl_xor(k3[q], mask, 64);
      ins3(k1[q], k2[q], k3[q], o1);
      ins3(k1[q], k2[q], k3[q], o2);
      ins3(k1[q], k2[q], k3[q], o3);
    }
  }

  // ---- epilogue bookkeeping in LDS (B buffers dead) ----
  int* sbest = (int*)smem;          // [64]
  int* lcnt = (int*)(smem + 256);   // 1 int
  int* flp = (int*)(smem + 512);    // [64] flagged px
  int* flq = (int*)(smem + 768);    // [64] zws slot
  if (t == 0) *lcnt = 0;
  __syncthreads();

  if (lcode == 0) {
#pragma unroll
    for (int q = 0; q < 4; ++q) {
      int row = w * 16 + lg * 4 + q;
      int p = p0 + row;
      int i1 = (int)(k1[q] & 1023u);
      sbest[row] = i1;
      out_idx[p] = (float)i1;
      float f1 = keyf(k1[q]);
      float g2 = keyf(k2[q]) - f1;
      float g3 = keyf(k3[q]) - f1;
      if (g3 < MARGIN) {
        int pos = atomicAdd(cnt + 1, 1);
        if (pos < capB) listB[pos] = p;
      } else if (g2 < MARGIN) {
        int pos = atomicAdd(cnt, 1);
        if (pos < capA) {
          listA[2 * pos] = p | (i1 << 16);
          listA[2 * pos + 1] = (int)(k2[q] & 1023u) |
                               ((int)(k3[q] & 1023u) << 16);
          if (pos < zcap) {
            int li = atomicAdd(lcnt, 1);
            flp[li] = p;
            flq[li] = pos;
          }
        }
      }
    }
  }
  __syncthreads();

  // ---- zq gather: coalesced over px ----
  {
    const int px = t & 63;
    const int best = sbest[px];
    const int ch0g = (t >> 6) * 64;
    const float* crow = cb + (size_t)best * CDIM + ch0g;
    float* ob = out_zq + (size_t)b * (CDIM * HWSZ) + (size_t)ch0g * HWSZ + hw0 + px;
#pragma unroll 4
    for (int c2 = 0; c2 < 64; c2 += 4) {
      float4 v = *(const float4*)(crow + c2);
      ob[(size_t)(c2 + 0) * HWSZ] = v.x;
      ob[(size_t)(c2 + 1) * HWSZ] = v.y;
      ob[(size_t)(c2 + 2) * HWSZ] = v.z;
      ob[(size_t)(c2 + 3) * HWSZ] = v.w;
    }
  }

  // ---- z-row dump for flagged px (lines are L2-hot from A loads) ----
  {
    const int nf = *lcnt;
    for (int e = 0; e < nf; ++e) {
      const int p = flp[e];
      const int slot = flq[e];
      const int bb = p >> 12;
      const int hh = p & (HWSZ - 1);
      zws[(size_t)slot * 256 + t] =
          z[(size_t)bb * (CDIM * HWSZ) + (size_t)t * HWSZ + hh];
    }
  }
}

// Resolve3: exact f64 check of the 3 candidate codes. One wave per entry;
// z from staged contiguous rows (fallback: strided global).
__launch_bounds__(256)
__global__ void vq_resolve3(const float* __restrict__ z,
                            const float* __restrict__ cb,
                            const double* __restrict__ cbn64,
                            float* __restrict__ out_zq,
                            float* __restrict__ out_idx,
                            const int* __restrict__ cnt,
                            const int* __restrict__ listA, int capA,
                            const float* __restrict__ zws, int zcap) {
  const int lane = threadIdx.x & 63;
  const int wid = (blockIdx.x * blockDim.x + threadIdx.x) >> 6;
  const int nw = (gridDim.x * blockDim.x) >> 6;
  int n = cnt[0];
  if (n > capA) n = capA;

  for (int i = wid; i < n; i += nw) {
    const int e0 = listA[2 * i];
    const int e1 = listA[2 * i + 1];
    const int p = e0 & 0xFFFF;
    int cand[3];
    cand[0] = (e0 >> 16) & 1023;
    cand[1] = e1 & 0xFFFF;
    cand[2] = (e1 >> 16) & 1023;
    const int b = p >> 12;
    const int hw = p & (HWSZ - 1);
    const int ch0 = lane * 4;

    double zv[4];
    if (i < zcap) {
      float4 zf = ((const float4*)(zws + (size_t)i * 256))[lane];
      zv[0] = (double)zf.x; zv[1] = (double)zf.y;
      zv[2] = (double)zf.z; zv[3] = (double)zf.w;
    } else {
      const float* zb = z + (size_t)b * (CDIM * HWSZ) + hw;
#pragma unroll
      for (int j = 0; j < 4; ++j) zv[j] = (double)zb[(size_t)(ch0 + j) * HWSZ];
    }

    double d[3];
#pragma unroll
    for (int tt = 0; tt < 3; ++tt) {
      float4 cv = *(const float4*)(cb + (size_t)cand[tt] * CDIM + ch0);
      double s = zv[0] * (double)cv.x;
      s = fma(zv[1], (double)cv.y, s);
      s = fma(zv[2], (double)cv.z, s);
      s = fma(zv[3], (double)cv.w, s);
#pragma unroll
      for (int off = 32; off; off >>= 1) s += __shfl_xor(s, off, 64);
      d[tt] = fma(-2.0, s, cbn64[cand[tt]]);
    }

    double bd = d[0];
    int bi = cand[0];
#pragma unroll
    for (int tt = 1; tt < 3; ++tt) {
      bool takes = (d[tt] < bd) || (d[tt] == bd && cand[tt] < bi);
      bd = takes ? d[tt] : bd;
      bi = takes ? cand[tt] : bi;
    }

    if (lane == 0) out_idx[p] = (float)bi;
    float4 cv = *(const float4*)(cb + (size_t)bi * CDIM + ch0);
    float* ob = out_zq + (size_t)b * (CDIM * HWSZ) + hw;
    ob[(size_t)(ch0 + 0) * HWSZ] = cv.x;
    ob[(size_t)(ch0 + 1) * HWSZ] = cv.y;
    ob[(size_t)(ch0 + 2) * HWSZ] = cv.z;
    ob[(size_t)(ch0 + 3) * HWSZ] = cv.w;
  }
}

// Fullscan: exact f64 full scan for triple-near-tie pixels. One block/pixel.
__launch_bounds__(256)
__global__ void vq_fullscan(const float* __restrict__ z,
                            const float* __restrict__ cb,
                            const double* __restrict__ cbn64,
                            float* __restrict__ out_zq,
                            float* __restrict__ out_idx,
                            const int* __restrict__ cnt,
                            const int* __restrict__ listB, int capB) {
  __shared__ double zl[256];
  __shared__ double sd[4];
  __shared__ int si[4];
  __shared__ int sfin;
  int n = cnt[1];
  if (n > capB) n = capB;
  const int t = threadIdx.x;
  const int w = t >> 6;
  const int lane = t & 63;

  for (int i = blockIdx.x; i < n; i += gridDim.x) {
    const int p = listB[i];
    const int b = p >> 12;
    const int hw = p & (HWSZ - 1);
    const float* zb = z + (size_t)b * (CDIM * HWSZ) + hw;
    zl[t] = (double)zb[(size_t)t * HWSZ];
    __syncthreads();

    const int g = t >> 2;
    const int sub = t & 3;
    const double* zq4 = zl + sub * 64;
    double bd = 1e300;
    int bi = 0;

    for (int j = 0; j < 16; ++j) {
      const int code = g + 64 * j;
      const float* crow = cb + (size_t)code * CDIM + sub * 64;
      double s = 0.0;
#pragma unroll
      for (int q4 = 0; q4 < 64; q4 += 4) {
        float4 cv = *(const float4*)(crow + q4);
        s = fma(zq4[q4 + 0], (double)cv.x, s);
        s = fma(zq4[q4 + 1], (double)cv.y, s);
        s = fma(zq4[q4 + 2], (double)cv.z, s);
        s = fma(zq4[q4 + 3], (double)cv.w, s);
      }
      s += __shfl_xor(s, 1, 64);
      s += __shfl_xor(s, 2, 64);
      double d = fma(-2.0, s, cbn64[code]);
      bool takes = (d < bd) || (d == bd && code < bi);
      bd = takes ? d : bd;
      bi = takes ? code : bi;
    }

#pragma unroll
    for (int off = 4; off <= 32; off <<= 1) {
      double od = __shfl_xor(bd, off, 64);
      int oi = __shfl_xor(bi, off, 64);
      bool takes = (od < bd) || (od == bd && oi < bi);
      bd = takes ? od : bd;
      bi = takes ? oi : bi;
    }
    if (lane == 0) { sd[w] = bd; si[w] = bi; }
    __syncthreads();
    if (t == 0) {
      double fd = sd[0];
      int fi = si[0];
#pragma unroll
      for (int k = 1; k < 4; ++k) {
        bool takes = (sd[k] < fd) || (sd[k] == fd && si[k] < fi);
        fd = takes ? sd[k] : fd;
        fi = takes ? si[k] : fi;
      }
      sfin = fi;
      out_idx[p] = (float)fi;
    }
    __syncthreads();
    const int best = sfin;
    float* ob = out_zq + (size_t)b * (CDIM * HWSZ) + hw;
    ob[(size_t)t * HWSZ] = cb[(size_t)best * CDIM + t];
    __syncthreads();
  }
}

extern "C" void kernel_launch(void* const* d_in, const int* in_sizes, int n_in,
                              void* d_out, int out_size, void* d_ws, size_t ws_size,
                              hipStream_t stream) {
  const float* z = (const float*)d_in[0];
  const float* cb = (const float*)d_in[1];
  float* out = (float*)d_out;
  float* out_zq = out;
  float* out_idx = out + ZQ_ELEMS;

  char* ws = (char*)d_ws;
  unsigned short* cbswz = (unsigned short*)(ws + WS_CBSWZ);
  double* cbn64 = (double*)(ws + WS_CBN64);
  float* cbn32p = (float*)(ws + WS_CBN32);
  int* cnt = (int*)(ws + WS_CNT);

  long long avail = (long long)ws_size - WS_LISTS;
  if (avail < 0) avail = 0;
  long long capA_ll = (avail / 4) / 8;          // listA <= 1/4 of avail
  if (capA_ll > NPIX) capA_ll = NPIX;
  int capA = (int)capA_ll;
  int* listA = (int*)(ws + WS_LISTS);
  long long rem = avail - (long long)capA * 8;
  long long capB_ll = rem / 8;                  // listB <= 1/2 of remainder
  if (capB_ll > NPIX) capB_ll = NPIX;
  if (capB_ll < 0) capB_ll = 0;
  int capB = (int)capB_ll;
  int* listB = (int*)(ws + WS_LISTS + (size_t)capA * 8);
  long long zoff = (WS_LISTS + (long long)capA * 8 + (long long)capB * 4 + 15) &
                   ~15LL;
  long long zcap_ll = ((long long)ws_size - zoff) / 1024;
  if (zcap_ll < 0) zcap_ll = 0;
  if (zcap_ll > capA) zcap_ll = capA;
  int zcap = (int)zcap_ll;
  float* zws = (float*)(ws + zoff);

  vq_prep<<<256, 256, 0, stream>>>(cb, cbswz, cbn64, cbn32p, cnt);
  vq_stage1<<<1024, 256, 32768, stream>>>(z, cb, cbswz, cbn32p, out_zq, out_idx,
                                          cnt, listA, capA, listB, capB,
                                          zws, zcap);
  vq_resolve3<<<1024, 256, 0, stream>>>(z, cb, cbn64, out_zq, out_idx,
                                        cnt, listA, capA, zws, zcap);
  vq_fullscan<<<256, 256, 0, stream>>>(z, cb, cbn64, out_zq, out_idx,
                                       cnt, listB, capB);
}

// Round 7
// 164.038 us; speedup vs baseline: 1.9355x; 1.1413x over previous
//
#include <hip/hip_runtime.h>

// PixelVectorQuantizer: z [16,256,64,64] f32, codebook [1024,256] f32
// outputs: zq (f32) + indices (as f32 values), concatenated in d_out.
//
// prep:     codebook -> (-2*c) bf16 swizzled 16-code chunks + f64 norms +
//           biased f32 norms. cnt zeroing.
// stage1:   bf16 MFMA distance GEMM, CODE-SPLIT: each wave = 32 px x 512
//           codes (af[2] shares each B-read across 2 MFMAs -> LDS traffic
//           halved vs 16px/wave, wave count stays 4096 = 4/SIMD).
//           u32 sort-keys (float-bits | code), v_med3_u32 top-3; cross-wave
//           merge in LDS. gap2 < MARGIN -> listA (+ z-row dump);
//           gap3 < MARGIN -> listB.
// resolve3: exact f64 check of 3 candidates; writes only if answer changes.
// fullscan: exact f64 full scan; writes only if answer changes.

#define HWSZ 4096
#define CDIM 256
#define KCODES 1024
#define NPIX 65536
#define ZQ_ELEMS (16 * 256 * 4096)
#define MARGIN 0.75f

// ws layout (fixed part)
#define WS_CBSWZ 0          // 64 chunks x 16 codes x 512 B = 524288 B
#define WS_CBN64 524288     // double[1024]
#define WS_CBN32 532480     // float[1024]  (= ||c||^2 + 512)
#define WS_CNT   536576     // int cntA, int cntB
#define WS_LISTS 536592     // listA (8B) | listB (4B) | zws (1KB rows)

typedef __attribute__((ext_vector_type(8))) short bf16x8;
typedef __attribute__((ext_vector_type(4))) float f32x4;
typedef __attribute__((ext_vector_type(4))) unsigned short us4;

#define MFMA16(a, b, c) __builtin_amdgcn_mfma_f32_16x16x32_bf16(a, b, c, 0, 0, 0)

__device__ __forceinline__ unsigned short f2bf(float f) {
  unsigned u = __float_as_uint(f);
  unsigned r = u + 0x7FFFu + ((u >> 16) & 1u);   // RNE
  return (unsigned short)(r >> 16);
}

__device__ __forceinline__ void gload_lds16(const void* g, void* l) {
  __builtin_amdgcn_global_load_lds(
      (const __attribute__((address_space(1))) unsigned int*)g,
      (__attribute__((address_space(3))) unsigned int*)l, 16, 0, 0);
}

// 3-op sorted-triple insert on u32 keys: min + 2x v_med3_u32.
__device__ __forceinline__ void ins3(unsigned& k1, unsigned& k2, unsigned& k3,
                                     unsigned k) {
  unsigned nk2, nk3;
  asm("v_med3_u32 %0, %1, %2, %3" : "=v"(nk2) : "v"(k1), "v"(k2), "v"(k));
  asm("v_med3_u32 %0, %1, %2, %3" : "=v"(nk3) : "v"(k2), "v"(k3), "v"(k));
  k1 = k1 < k ? k1 : k;
  k2 = nk2;
  k3 = nk3;
}

__device__ __forceinline__ float keyf(unsigned k) {
  return __uint_as_float(k & 0xFFFFFC00u);
}

// Fused prep: 256 blocks x 256 thr; block b -> codes 4b..4b+3 (wave/code).
// cbswz chunk K = (code>>9)*32 + ((code>>4)&31): 16 codes x 512 B, row =
// code&15, bytes XOR-swizzled by ((r&7)<<4).
__global__ void vq_prep(const float* __restrict__ cb,
                        unsigned short* __restrict__ cbswz,
                        double* __restrict__ cbn64,
                        float* __restrict__ cbn32p,
                        int* __restrict__ cnt) {
  const int t = threadIdx.x;
  if (blockIdx.x == 0 && t == 0) { cnt[0] = 0; cnt[1] = 0; }
  const int code = blockIdx.x * 4 + (t >> 6);
  const int lane = t & 63;
  const int c4 = lane * 4;

  float4 v = *(const float4*)(cb + (size_t)code * CDIM + c4);
  us4 hv;  // store -2*c (exact power-of-2 scale) so MFMA yields -2 z.c
  hv.x = f2bf(-2.f * v.x); hv.y = f2bf(-2.f * v.y);
  hv.z = f2bf(-2.f * v.z); hv.w = f2bf(-2.f * v.w);
  const int K = (code >> 9) * 32 + ((code >> 4) & 31);
  unsigned r = (unsigned)(code & 15);
  unsigned off = ((r << 9) + (unsigned)(c4 << 1)) ^ ((r & 7) << 4);
  *(us4*)((char*)cbswz + (size_t)K * 8192 + off) = hv;

  double s = (double)v.x * v.x;
  s = fma((double)v.y, (double)v.y, s);
  s = fma((double)v.z, (double)v.z, s);
  s = fma((double)v.w, (double)v.w, s);
#pragma unroll
  for (int o = 32; o; o >>= 1) s += __shfl_xor(s, o, 64);
  if (lane == 0) {
    cbn64[code] = s;
    cbn32p[code] = (float)s + 512.0f;  // bias keeps keys positive
  }
}

// Stage 1: 1024 blocks x 256 thr (4 waves), 64 px/block.
// wave w: px-half h=w>>1 (32 px), code-half q=w&1 (512 codes).
// LDS 36 KB: [2 dbuf][2 half][8 KB chunk] = 32 KB + norm table 4 KB.
__launch_bounds__(256)
__global__ void vq_stage1(const float* __restrict__ z,
                          const float* __restrict__ cb,
                          const unsigned short* __restrict__ cbswz,
                          const float* __restrict__ cbn32p,
                          float* __restrict__ out_zq,
                          float* __restrict__ out_idx,
                          int* __restrict__ cnt,      // [cntA, cntB]
                          int* __restrict__ listA, int capA,
                          int* __restrict__ listB, int capB,
                          float* __restrict__ zws, int zcap) {
  extern __shared__ char smem[];
  const int t = threadIdx.x;
  const int w = t >> 6;
  const int lane = t & 63;
  const int lg = lane >> 4;
  const int lcode = lane & 15;
  const int h = w >> 1;   // px half
  const int q = w & 1;    // code half
  const int p0 = blockIdx.x * 64;
  const int b = p0 >> 12;
  const int hw0 = p0 & (HWSZ - 1);
  const float* zb = z + (size_t)b * (CDIM * HWSZ) + hw0;

  float* nrm = (float*)(smem + 32768);  // [1024]
  {
    float4 nv = *(const float4*)(cbn32p + t * 4);
    *(float4*)(nrm + t * 4) = nv;
  }

  // ---- prologue: stage chunk (q,0) -> dbuf0 (waves pair-split 8KB) ----
  {
    const char* gsrc = (const char*)cbswz + (size_t)(q * 32) * 8192 +
                       (h * 4) * 1024 + lane * 16;
    char* ldst = smem + q * 8192 + (h * 4) * 1024 + lane * 16;
#pragma unroll
    for (int j = 0; j < 4; ++j)
      gload_lds16(gsrc + j * 1024, ldst + j * 1024);
  }

  // ---- A fragments: 32 px x 256 ch per wave, direct global -> regs ----
  bf16x8 af[2][8];
#pragma unroll
  for (int T = 0; T < 2; ++T) {
    const float* zr = zb + (h * 32 + T * 16 + lcode);
#pragma unroll
    for (int kk = 0; kk < 8; ++kk) {
      const int ch0 = kk * 32 + lg * 8;
      bf16x8 f;
#pragma unroll
      for (int j = 0; j < 8; ++j)
        f[j] = (short)f2bf(zr[(size_t)(ch0 + j) * HWSZ]);
      af[T][kk] = f;
    }
  }
  __syncthreads();

  unsigned k1[2][4], k2[2][4], k3[2][4];
#pragma unroll
  for (int T = 0; T < 2; ++T)
#pragma unroll
    for (int q4 = 0; q4 < 4; ++q4) {
      k1[T][q4] = 0xFFFFFFFFu; k2[T][q4] = 0xFFFFFFFFu; k3[T][q4] = 0xFFFFFFFFu;
    }

  const unsigned rsw = ((unsigned)(lcode & 7)) << 4;
  const unsigned rbase = ((unsigned)lcode << 9) + (((unsigned)lg) << 4);
  const char* myhalf = smem + q * 8192;
  const int nrm0 = q * 512 + lcode;

  for (int c = 0; c < 32; ++c) {
    const char* rbuf = myhalf + (c & 1) * 16384;
    if (c < 31) {
      const char* gsrc = (const char*)cbswz + (size_t)(q * 32 + c + 1) * 8192 +
                         (h * 4) * 1024 + lane * 16;
      char* ldst = smem + ((c + 1) & 1) * 16384 + q * 8192 +
                   (h * 4) * 1024 + lane * 16;
#pragma unroll
      for (int j = 0; j < 4; ++j)
        gload_lds16(gsrc + j * 1024, ldst + j * 1024);
    }
    f32x4 acc0 = {0.f, 0.f, 0.f, 0.f};
    f32x4 acc1 = {0.f, 0.f, 0.f, 0.f};
#pragma unroll
    for (int kk = 0; kk < 8; ++kk) {
      bf16x8 bf = *(const bf16x8*)(rbuf + ((rbase + ((unsigned)kk << 6)) ^ rsw));
      acc0 = MFMA16(af[0][kk], bf, acc0);
      acc1 = MFMA16(af[1][kk], bf, acc1);
    }
    const unsigned code = (unsigned)(nrm0 + c * 16);
    const float cn = nrm[code];
#pragma unroll
    for (int T = 0; T < 2; ++T)
#pragma unroll
      for (int q4 = 0; q4 < 4; ++q4) {
        float m = cn + ((T == 0) ? acc0[q4] : acc1[q4]);  // acc = -2 z.c
        unsigned key = (__float_as_uint(m) & 0xFFFFFC00u) | code;
        ins3(k1[T][q4], k2[T][q4], k3[T][q4], key);
      }
    __syncthreads();
  }

  // ---- cross-lane top-3 merge over the 16-column group ----
#pragma unroll
  for (int mask = 1; mask <= 8; mask <<= 1) {
#pragma unroll
    for (int T = 0; T < 2; ++T)
#pragma unroll
      for (int q4 = 0; q4 < 4; ++q4) {
        unsigned o1 = __shfl_xor(k1[T][q4], mask, 64);
        unsigned o2 = __shfl_xor(k2[T][q4], mask, 64);
        unsigned o3 = __shfl_xor(k3[T][q4], mask, 64);
        ins3(k1[T][q4], k2[T][q4], k3[T][q4], o1);
        ins3(k1[T][q4], k2[T][q4], k3[T][q4], o2);
        ins3(k1[T][q4], k2[T][q4], k3[T][q4], o3);
      }
  }

  // ---- cross-wave merge (code halves) via LDS ----
  unsigned* mk = (unsigned*)smem;   // [64 px][2 half][3]
  int* lcnt = (int*)(smem + 2304);
  if (t == 0) *lcnt = 0;
  if (lcode == 0) {
#pragma unroll
    for (int T = 0; T < 2; ++T)
#pragma unroll
      for (int q4 = 0; q4 < 4; ++q4) {
        int row = h * 32 + T * 16 + lg * 4 + q4;
        unsigned* d = mk + (row * 2 + q) * 3;
        d[0] = k1[T][q4]; d[1] = k2[T][q4]; d[2] = k3[T][q4];
      }
  }
  __syncthreads();

  int* sbest = (int*)(smem + 2048);  // [64] (above mk's 1536 B)
  int* flp = (int*)(smem + 2560);    // [64]
  int* flq = (int*)(smem + 2816);    // [64]
  if (t < 64) {
    unsigned a1 = mk[t * 6 + 0], a2 = mk[t * 6 + 1], a3 = mk[t * 6 + 2];
    ins3(a1, a2, a3, mk[t * 6 + 3]);
    ins3(a1, a2, a3, mk[t * 6 + 4]);
    ins3(a1, a2, a3, mk[t * 6 + 5]);
    const int p = p0 + t;
    const int i1 = (int)(a1 & 1023u);
    sbest[t] = i1;
    out_idx[p] = (float)i1;
    float f1 = keyf(a1);
    float g2 = keyf(a2) - f1;
    float g3 = keyf(a3) - f1;
    if (g3 < MARGIN) {
      int pos = atomicAdd(cnt + 1, 1);
      if (pos < capB) listB[pos] = p;
    } else if (g2 < MARGIN) {
      int pos = atomicAdd(cnt, 1);
      if (pos < capA) {
        listA[2 * pos] = p | (i1 << 16);
        listA[2 * pos + 1] = (int)(a2 & 1023u) | ((int)(a3 & 1023u) << 16);
        if (pos < zcap) {
          int li = atomicAdd(lcnt, 1);
          flp[li] = p;
          flq[li] = pos;
        }
      }
    }
  }
  __syncthreads();

  // ---- zq gather: coalesced over px ----
  {
    const int px = t & 63;
    const int best = sbest[px];
    const int ch0g = (t >> 6) * 64;
    const float* crow = cb + (size_t)best * CDIM + ch0g;
    float* ob = out_zq + (size_t)b * (CDIM * HWSZ) + (size_t)ch0g * HWSZ + hw0 + px;
#pragma unroll 4
    for (int c2 = 0; c2 < 64; c2 += 4) {
      float4 v = *(const float4*)(crow + c2);
      ob[(size_t)(c2 + 0) * HWSZ] = v.x;
      ob[(size_t)(c2 + 1) * HWSZ] = v.y;
      ob[(size_t)(c2 + 2) * HWSZ] = v.z;
      ob[(size_t)(c2 + 3) * HWSZ] = v.w;
    }
  }

  // ---- z-row dump for flagged px (lines are L2-hot from A loads) ----
  {
    const int nf = *lcnt;
    for (int e = 0; e < nf; ++e) {
      const int p = flp[e];
      const int slot = flq[e];
      const int bb = p >> 12;
      const int hh = p & (HWSZ - 1);
      zws[(size_t)slot * 256 + t] =
          z[(size_t)bb * (CDIM * HWSZ) + (size_t)t * HWSZ + hh];
    }
  }
}

// Resolve3: exact f64 check of the 3 candidate codes. One wave per entry.
// Writes only when the exact argmin differs from stage1's pick.
__launch_bounds__(256)
__global__ void vq_resolve3(const float* __restrict__ z,
                            const float* __restrict__ cb,
                            const double* __restrict__ cbn64,
                            float* __restrict__ out_zq,
                            float* __restrict__ out_idx,
                            const int* __restrict__ cnt,
                            const int* __restrict__ listA, int capA,
                            const float* __restrict__ zws, int zcap) {
  const int lane = threadIdx.x & 63;
  const int wid = (blockIdx.x * blockDim.x + threadIdx.x) >> 6;
  const int nw = (gridDim.x * blockDim.x) >> 6;
  int n = cnt[0];
  if (n > capA) n = capA;

  for (int i = wid; i < n; i += nw) {
    const int e0 = listA[2 * i];
    const int e1 = listA[2 * i + 1];
    const int p = e0 & 0xFFFF;
    int cand[3];
    cand[0] = (e0 >> 16) & 1023;
    cand[1] = e1 & 0xFFFF;
    cand[2] = (e1 >> 16) & 1023;
    const int b = p >> 12;
    const int hw = p & (HWSZ - 1);
    const int ch0 = lane * 4;

    double zv[4];
    if (i < zcap) {
      float4 zf = ((const float4*)(zws + (size_t)i * 256))[lane];
      zv[0] = (double)zf.x; zv[1] = (double)zf.y;
      zv[2] = (double)zf.z; zv[3] = (double)zf.w;
    } else {
      const float* zb = z + (size_t)b * (CDIM * HWSZ) + hw;
#pragma unroll
      for (int j = 0; j < 4; ++j) zv[j] = (double)zb[(size_t)(ch0 + j) * HWSZ];
    }

    double d[3];
#pragma unroll
    for (int tt = 0; tt < 3; ++tt) {
      float4 cv = *(const float4*)(cb + (size_t)cand[tt] * CDIM + ch0);
      double s = zv[0] * (double)cv.x;
      s = fma(zv[1], (double)cv.y, s);
      s = fma(zv[2], (double)cv.z, s);
      s = fma(zv[3], (double)cv.w, s);
#pragma unroll
      for (int off = 32; off; off >>= 1) s += __shfl_xor(s, off, 64);
      d[tt] = fma(-2.0, s, cbn64[cand[tt]]);
    }

    double bd = d[0];
    int bi = cand[0];
#pragma unroll
    for (int tt = 1; tt < 3; ++tt) {
      bool takes = (d[tt] < bd) || (d[tt] == bd && cand[tt] < bi);
      bd = takes ? d[tt] : bd;
      bi = takes ? cand[tt] : bi;
    }

    if (bi != cand[0]) {  // stage1 was wrong: rewrite idx + zq row
      if (lane == 0) out_idx[p] = (float)bi;
      float4 cv = *(const float4*)(cb + (size_t)bi * CDIM + ch0);
      float* ob = out_zq + (size_t)b * (CDIM * HWSZ) + hw;
      ob[(size_t)(ch0 + 0) * HWSZ] = cv.x;
      ob[(size_t)(ch0 + 1) * HWSZ] = cv.y;
      ob[(size_t)(ch0 + 2) * HWSZ] = cv.z;
      ob[(size_t)(ch0 + 3) * HWSZ] = cv.w;
    }
  }
}

// Fullscan: exact f64 full scan for triple-near-tie pixels. One block/pixel.
__launch_bounds__(256)
__global__ void vq_fullscan(const float* __restrict__ z,
                            const float* __restrict__ cb,
                            const double* __restrict__ cbn64,
                            float* __restrict__ out_zq,
                            float* __restrict__ out_idx,
                            const int* __restrict__ cnt,
                            const int* __restrict__ listB, int capB) {
  __shared__ double zl[256];
  __shared__ double sd[4];
  __shared__ int si[4];
  __shared__ int sfin;
  int n = cnt[1];
  if (n > capB) n = capB;
  const int t = threadIdx.x;
  const int w = t >> 6;
  const int lane = t & 63;

  for (int i = blockIdx.x; i < n; i += gridDim.x) {
    const int p = listB[i];
    const int b = p >> 12;
    const int hw = p & (HWSZ - 1);
    const float* zb = z + (size_t)b * (CDIM * HWSZ) + hw;
    zl[t] = (double)zb[(size_t)t * HWSZ];
    __syncthreads();

    const int g = t >> 2;
    const int sub = t & 3;
    const double* zq4 = zl + sub * 64;
    double bd = 1e300;
    int bi = 0;

    for (int j = 0; j < 16; ++j) {
      const int code = g + 64 * j;
      const float* crow = cb + (size_t)code * CDIM + sub * 64;
      double s = 0.0;
#pragma unroll
      for (int q4 = 0; q4 < 64; q4 += 4) {
        float4 cv = *(const float4*)(crow + q4);
        s = fma(zq4[q4 + 0], (double)cv.x, s);
        s = fma(zq4[q4 + 1], (double)cv.y, s);
        s = fma(zq4[q4 + 2], (double)cv.z, s);
        s = fma(zq4[q4 + 3], (double)cv.w, s);
      }
      s += __shfl_xor(s, 1, 64);
      s += __shfl_xor(s, 2, 64);
      double d = fma(-2.0, s, cbn64[code]);
      bool takes = (d < bd) || (d == bd && code < bi);
      bd = takes ? d : bd;
      bi = takes ? code : bi;
    }

#pragma unroll
    for (int off = 4; off <= 32; off <<= 1) {
      double od = __shfl_xor(bd, off, 64);
      int oi = __shfl_xor(bi, off, 64);
      bool takes = (od < bd) || (od == bd && oi < bi);
      bd = takes ? od : bd;
      bi = takes ? oi : bi;
    }
    if (lane == 0) { sd[w] = bd; si[w] = bi; }
    __syncthreads();
    if (t == 0) {
      double fd = sd[0];
      int fi = si[0];
#pragma unroll
      for (int k = 1; k < 4; ++k) {
        bool takes = (sd[k] < fd) || (sd[k] == fd && si[k] < fi);
        fd = takes ? sd[k] : fd;
        fi = takes ? si[k] : fi;
      }
      const int old = (int)out_idx[p];
      if (fi != old) out_idx[p] = (float)fi;
      sfin = (fi != old) ? fi : -1;
    }
    __syncthreads();
    const int best = sfin;
    if (best >= 0) {
      float* ob = out_zq + (size_t)b * (CDIM * HWSZ) + hw;
      ob[(size_t)t * HWSZ] = cb[(size_t)best * CDIM + t];
    }
    __syncthreads();
  }
}

extern "C" void kernel_launch(void* const* d_in, const int* in_sizes, int n_in,
                              void* d_out, int out_size, void* d_ws, size_t ws_size,
                              hipStream_t stream) {
  const float* z = (const float*)d_in[0];
  const float* cb = (const float*)d_in[1];
  float* out = (float*)d_out;
  float* out_zq = out;
  float* out_idx = out + ZQ_ELEMS;

  char* ws = (char*)d_ws;
  unsigned short* cbswz = (unsigned short*)(ws + WS_CBSWZ);
  double* cbn64 = (double*)(ws + WS_CBN64);
  float* cbn32p = (float*)(ws + WS_CBN32);
  int* cnt = (int*)(ws + WS_CNT);

  long long avail = (long long)ws_size - WS_LISTS;
  if (avail < 0) avail = 0;
  long long capA_ll = (avail / 4) / 8;          // listA <= 1/4 of avail
  if (capA_ll > NPIX) capA_ll = NPIX;
  int capA = (int)capA_ll;
  int* listA = (int*)(ws + WS_LISTS);
  long long rem = avail - (long long)capA * 8;
  long long capB_ll = rem / 8;                  // listB <= 1/2 of remainder
  if (capB_ll > NPIX) capB_ll = NPIX;
  if (capB_ll < 0) capB_ll = 0;
  int capB = (int)capB_ll;
  int* listB = (int*)(ws + WS_LISTS + (size_t)capA * 8);
  long long zoff = (WS_LISTS + (long long)capA * 8 + (long long)capB * 4 + 15) &
                   ~15LL;
  long long zcap_ll = ((long long)ws_size - zoff) / 1024;
  if (zcap_ll < 0) zcap_ll = 0;
  if (zcap_ll > capA) zcap_ll = capA;
  int zcap = (int)zcap_ll;
  float* zws = (float*)(ws + zoff);

  vq_prep<<<256, 256, 0, stream>>>(cb, cbswz, cbn64, cbn32p, cnt);
  vq_stage1<<<1024, 256, 36864, stream>>>(z, cb, cbswz, cbn32p, out_zq, out_idx,
                                          cnt, listA, capA, listB, capB,
                                          zws, zcap);
  vq_resolve3<<<1024, 256, 0, stream>>>(z, cb, cbn64, out_zq, out_idx,
                                        cnt, listA, capA, zws, zcap);
  vq_fullscan<<<256, 256, 0, stream>>>(z, cb, cbn64, out_zq, out_idx,
                                       cnt, listB, capB);
}

// Round 8
// 155.555 us; speedup vs baseline: 2.0411x; 1.0545x over previous
//
#include <hip/hip_runtime.h>

// PixelVectorQuantizer: z [16,256,64,64] f32, codebook [1024,256] f32
// outputs: zq (f32) + indices (as f32 values), concatenated in d_out.
//
// prep:     codebook -> (-2*c) bf16 in FRAGMENT-STREAM order
//           [chunk16][kk][code][lg] + f64 norms + biased f32 norms.
// stage1:   bf16 MFMA distance GEMM, code-split (wave = 32px x 512 codes),
//           TRIPLE-buffered LDS chunks, raw s_barrier + counted vmcnt(4)
//           (never 0 in-loop), contiguous conflict-free ds_read_b128 with
//           imm offsets. u32 sort-keys, v_med3_u32 top-3; cross-wave merge.
// resolve3: exact f64 check of 3 candidates (z from staged rows).
// fullscan: exact f64 full scan for triple-near-ties.

#define HWSZ 4096
#define CDIM 256
#define KCODES 1024
#define NPIX 65536
#define ZQ_ELEMS (16 * 256 * 4096)
#define MARGIN 0.75f

// ws layout (fixed part)
#define WS_CBSWZ 0          // 64 chunks x 8 KB fragment-stream = 524288 B
#define WS_CBN64 524288     // double[1024]
#define WS_CBN32 532480     // float[1024]  (= ||c||^2 + 512)
#define WS_CNT   536576     // int cntA, int cntB
#define WS_LISTS 536592     // listA (8B) | listB (4B) | zws (1KB rows)

typedef __attribute__((ext_vector_type(8))) short bf16x8;
typedef __attribute__((ext_vector_type(4))) float f32x4;
typedef __attribute__((ext_vector_type(4))) unsigned short us4;

#define MFMA16(a, b, c) __builtin_amdgcn_mfma_f32_16x16x32_bf16(a, b, c, 0, 0, 0)

__device__ __forceinline__ unsigned short f2bf(float f) {
  unsigned u = __float_as_uint(f);
  unsigned r = u + 0x7FFFu + ((u >> 16) & 1u);   // RNE
  return (unsigned short)(r >> 16);
}

__device__ __forceinline__ void gload_lds16(const void* g, void* l) {
  __builtin_amdgcn_global_load_lds(
      (const __attribute__((address_space(1))) unsigned int*)g,
      (__attribute__((address_space(3))) unsigned int*)l, 16, 0, 0);
}

// 3-op sorted-triple insert on u32 keys: min + 2x v_med3_u32.
__device__ __forceinline__ void ins3(unsigned& k1, unsigned& k2, unsigned& k3,
                                     unsigned k) {
  unsigned nk2, nk3;
  asm("v_med3_u32 %0, %1, %2, %3" : "=v"(nk2) : "v"(k1), "v"(k2), "v"(k));
  asm("v_med3_u32 %0, %1, %2, %3" : "=v"(nk3) : "v"(k2), "v"(k3), "v"(k));
  k1 = k1 < k ? k1 : k;
  k2 = nk2;
  k3 = nk3;
}

__device__ __forceinline__ float keyf(unsigned k) {
  return __uint_as_float(k & 0xFFFFFC00u);
}

// Fused prep: 256 blocks x 256 thr; block b -> codes 4b..4b+3 (wave/code).
// Stream layout: chunk K = (code>>9)*32 + ((code>>4)&31) holds 16 codes;
// byte offset = kk*1024 + (code&15)*64 + lg*16 + (ch&7)*2 where
// kk = ch>>5, lg = (ch>>3)&3.  (Matches MFMA B-frag lane order: lane
// reads a contiguous 16 B at (lane&15)*64 + (lane>>4)*16 + kk*1024.)
__global__ void vq_prep(const float* __restrict__ cb,
                        unsigned short* __restrict__ cbswz,
                        double* __restrict__ cbn64,
                        float* __restrict__ cbn32p,
                        int* __restrict__ cnt) {
  const int t = threadIdx.x;
  if (blockIdx.x == 0 && t == 0) { cnt[0] = 0; cnt[1] = 0; }
  const int code = blockIdx.x * 4 + (t >> 6);
  const int lane = t & 63;
  const int c4 = lane * 4;

  float4 v = *(const float4*)(cb + (size_t)code * CDIM + c4);
  us4 hv;  // store -2*c (exact power-of-2 scale) so MFMA yields -2 z.c
  hv.x = f2bf(-2.f * v.x); hv.y = f2bf(-2.f * v.y);
  hv.z = f2bf(-2.f * v.z); hv.w = f2bf(-2.f * v.w);
  const int K = (code >> 9) * 32 + ((code >> 4) & 31);
  const int kk = c4 >> 5;
  const int lg = (c4 >> 3) & 3;
  const int within = (c4 & 7) * 2;
  size_t off = (size_t)K * 8192 + kk * 1024 + (code & 15) * 64 + lg * 16 + within;
  *(us4*)((char*)cbswz + off) = hv;

  double s = (double)v.x * v.x;
  s = fma((double)v.y, (double)v.y, s);
  s = fma((double)v.z, (double)v.z, s);
  s = fma((double)v.w, (double)v.w, s);
#pragma unroll
  for (int o = 32; o; o >>= 1) s += __shfl_xor(s, o, 64);
  if (lane == 0) {
    cbn64[code] = s;
    cbn32p[code] = (float)s + 512.0f;  // bias keeps keys positive
  }
}

// Stage 1: 1024 blocks x 256 thr (4 waves), 64 px/block.
// wave w: px-half h=w>>1 (32 px), code-half q=w&1 (512 codes).
// LDS 52 KB: 3 chunk-buffers x [2 half][8 KB] = 48 KB + norm/scratch 4 KB.
__launch_bounds__(256)
__global__ void vq_stage1(const float* __restrict__ z,
                          const float* __restrict__ cb,
                          const unsigned short* __restrict__ cbswz,
                          const float* __restrict__ cbn32p,
                          float* __restrict__ out_zq,
                          float* __restrict__ out_idx,
                          int* __restrict__ cnt,      // [cntA, cntB]
                          int* __restrict__ listA, int capA,
                          int* __restrict__ listB, int capB,
                          float* __restrict__ zws, int zcap) {
  extern __shared__ char smem[];
  const int t = threadIdx.x;
  const int w = t >> 6;
  const int lane = t & 63;
  const int lg = lane >> 4;
  const int lcode = lane & 15;
  const int h = w >> 1;   // px half
  const int q = w & 1;    // code half
  const int p0 = blockIdx.x * 64;
  const int b = p0 >> 12;
  const int hw0 = p0 & (HWSZ - 1);
  const float* zb = z + (size_t)b * (CDIM * HWSZ) + hw0;

  char* const bb0 = smem + q * 8192;
  char* const bb1 = smem + 16384 + q * 8192;
  char* const bb2 = smem + 32768 + q * 8192;
  float* nrm = (float*)(smem + 49152);   // [1024]; reused as scratch later
  char* scratch = smem + 49152;

  const int stl = h * 4096 + lane * 16;
  const char* cbbase = (const char*)cbswz + (size_t)q * 262144 + stl;

#define STAGE(CIDX, SBUF)                                             \
  {                                                                   \
    const char* gs_ = cbbase + ((size_t)(CIDX) << 13);                \
    char* ld_ = (SBUF) + stl;                                         \
    gload_lds16(gs_, ld_);                                            \
    gload_lds16(gs_ + 1024, ld_ + 1024);                              \
    gload_lds16(gs_ + 2048, ld_ + 2048);                              \
    gload_lds16(gs_ + 3072, ld_ + 3072);                              \
  }

  // ---- prologue: stage chunks 0,1 (complete before loop via syncthreads)
  STAGE(0, bb0);
  STAGE(1, bb1);

  // ---- A fragments: 32 px x 256 ch per wave, direct global -> regs ----
  bf16x8 af[2][8];
#pragma unroll
  for (int T = 0; T < 2; ++T) {
    const float* zr = zb + (h * 32 + T * 16 + lcode);
#pragma unroll
    for (int kk = 0; kk < 8; ++kk) {
      const int ch0 = kk * 32 + lg * 8;
      bf16x8 f;
#pragma unroll
      for (int j = 0; j < 8; ++j)
        f[j] = (short)f2bf(zr[(size_t)(ch0 + j) * HWSZ]);
      af[T][kk] = f;
    }
  }

  // ---- norm table -> LDS ----
  *(float4*)(nrm + t * 4) = *(const float4*)(cbn32p + t * 4);
  __syncthreads();   // full drain ONCE: chunks 0,1 + A-loads + nrm all done

  unsigned k1[2][4], k2[2][4], k3[2][4];
#pragma unroll
  for (int T = 0; T < 2; ++T)
#pragma unroll
    for (int q4 = 0; q4 < 4; ++q4) {
      k1[T][q4] = 0xFFFFFFFFu; k2[T][q4] = 0xFFFFFFFFu; k3[T][q4] = 0xFFFFFFFFu;
    }

  const int bq = lcode * 64 + lg * 16;          // B-frag lane offset
  const float* nrmp = nrm + q * 512 + lcode;    // per-lane norm pointer
  const int kbase = q * 512 + lcode;

  // body: counted vmcnt (never 0 in-loop) + raw barrier, stage c+2 into the
  // third buffer (no WAR with current reads), contiguous imm-offset ds_reads.
#define BODY(CIDX, RBUF, SBUF, DOSTAGE, WN)                           \
  {                                                                   \
    asm volatile("s_waitcnt vmcnt(" WN ")" ::: "memory");             \
    __builtin_amdgcn_s_barrier();                                     \
    __builtin_amdgcn_sched_barrier(0);                                \
    if (DOSTAGE) STAGE((CIDX) + 2, SBUF);                             \
    const char* pb_ = (RBUF) + bq;                                    \
    f32x4 acc0 = {0.f, 0.f, 0.f, 0.f};                                \
    f32x4 acc1 = {0.f, 0.f, 0.f, 0.f};                                \
    _Pragma("unroll")                                                 \
    for (int kk = 0; kk < 8; ++kk) {                                  \
      bf16x8 bf_ = *(const bf16x8*)(pb_ + kk * 1024);                 \
      acc0 = MFMA16(af[0][kk], bf_, acc0);                            \
      acc1 = MFMA16(af[1][kk], bf_, acc1);                            \
    }                                                                 \
    const unsigned code_ = (unsigned)(kbase + (CIDX) * 16);           \
    const float cn_ = nrmp[(CIDX) * 16];                              \
    _Pragma("unroll")                                                 \
    for (int q4 = 0; q4 < 4; ++q4) {                                  \
      float m0_ = cn_ + acc0[q4];                                     \
      ins3(k1[0][q4], k2[0][q4], k3[0][q4],                           \
           (__float_as_uint(m0_) & 0xFFFFFC00u) | code_);             \
      float m1_ = cn_ + acc1[q4];                                     \
      ins3(k1[1][q4], k2[1][q4], k3[1][q4],                           \
           (__float_as_uint(m1_) & 0xFFFFFC00u) | code_);             \
    }                                                                 \
  }

#pragma unroll 1
  for (int c3 = 0; c3 < 30; c3 += 3) {
    BODY(c3 + 0, bb0, bb2, 1, "4");   // stages c3+2 -> buf2
    BODY(c3 + 1, bb1, bb0, 1, "4");   // stages c3+3 -> buf0
    BODY(c3 + 2, bb2, bb1, 1, "4");   // stages c3+4 -> buf1
  }
  BODY(30, bb0, bb2, 0, "4");
  BODY(31, bb1, bb0, 0, "0");
#undef BODY
#undef STAGE

  // ---- cross-lane top-3 merge over the 16-column group ----
#pragma unroll
  for (int mask = 1; mask <= 8; mask <<= 1) {
#pragma unroll
    for (int T = 0; T < 2; ++T)
#pragma unroll
      for (int q4 = 0; q4 < 4; ++q4) {
        unsigned o1 = __shfl_xor(k1[T][q4], mask, 64);
        unsigned o2 = __shfl_xor(k2[T][q4], mask, 64);
        unsigned o3 = __shfl_xor(k3[T][q4], mask, 64);
        ins3(k1[T][q4], k2[T][q4], k3[T][q4], o1);
        ins3(k1[T][q4], k2[T][q4], k3[T][q4], o2);
        ins3(k1[T][q4], k2[T][q4], k3[T][q4], o3);
      }
  }

  // ---- cross-wave merge (code halves) via scratch LDS ----
  // scratch overlaps nrm[0..576): body-31 reads nrm at >=496+... only for
  // q=0 (bytes 1984+) and >=1008 for q=1 -> mk (1536 B) is race-free.
  unsigned* mk = (unsigned*)scratch;        // [64 px][2 half][3] = 1536 B
  int* sbest = (int*)(scratch + 1536);      // [64]
  int* flp = (int*)(scratch + 1792);        // [64]
  int* flq = (int*)(scratch + 2048);        // [64]
  int* lcnt = (int*)(scratch + 2304);
  if (t == 0) *lcnt = 0;
  if (lcode == 0) {
#pragma unroll
    for (int T = 0; T < 2; ++T)
#pragma unroll
      for (int q4 = 0; q4 < 4; ++q4) {
        int row = h * 32 + T * 16 + lg * 4 + q4;
        unsigned* d = mk + (row * 2 + q) * 3;
        d[0] = k1[T][q4]; d[1] = k2[T][q4]; d[2] = k3[T][q4];
      }
  }
  __syncthreads();

  if (t < 64) {
    unsigned a1 = mk[t * 6 + 0], a2 = mk[t * 6 + 1], a3 = mk[t * 6 + 2];
    ins3(a1, a2, a3, mk[t * 6 + 3]);
    ins3(a1, a2, a3, mk[t * 6 + 4]);
    ins3(a1, a2, a3, mk[t * 6 + 5]);
    const int p = p0 + t;
    const int i1 = (int)(a1 & 1023u);
    sbest[t] = i1;
    out_idx[p] = (float)i1;
    float f1 = keyf(a1);
    float g2 = keyf(a2) - f1;
    float g3 = keyf(a3) - f1;
    if (g3 < MARGIN) {
      int pos = atomicAdd(cnt + 1, 1);
      if (pos < capB) listB[pos] = p;
    } else if (g2 < MARGIN) {
      int pos = atomicAdd(cnt, 1);
      if (pos < capA) {
        listA[2 * pos] = p | (i1 << 16);
        listA[2 * pos + 1] = (int)(a2 & 1023u) | ((int)(a3 & 1023u) << 16);
        if (pos < zcap) {
          int li = atomicAdd(lcnt, 1);
          flp[li] = p;
          flq[li] = pos;
        }
      }
    }
  }
  __syncthreads();

  // ---- zq gather: coalesced over px ----
  {
    const int px = t & 63;
    const int best = sbest[px];
    const int ch0g = (t >> 6) * 64;
    const float* crow = cb + (size_t)best * CDIM + ch0g;
    float* ob = out_zq + (size_t)b * (CDIM * HWSZ) + (size_t)ch0g * HWSZ + hw0 + px;
#pragma unroll 4
    for (int c2 = 0; c2 < 64; c2 += 4) {
      float4 v = *(const float4*)(crow + c2);
      ob[(size_t)(c2 + 0) * HWSZ] = v.x;
      ob[(size_t)(c2 + 1) * HWSZ] = v.y;
      ob[(size_t)(c2 + 2) * HWSZ] = v.z;
      ob[(size_t)(c2 + 3) * HWSZ] = v.w;
    }
  }

  // ---- z-row dump for flagged px (lines are L2-hot from A loads) ----
  {
    const int nf = *lcnt;
    for (int e = 0; e < nf; ++e) {
      const int p = flp[e];
      const int slot = flq[e];
      const int bb = p >> 12;
      const int hh = p & (HWSZ - 1);
      zws[(size_t)slot * 256 + t] =
          z[(size_t)bb * (CDIM * HWSZ) + (size_t)t * HWSZ + hh];
    }
  }
}

// Resolve3: exact f64 check of the 3 candidate codes. One wave per entry.
// Writes only when the exact argmin differs from stage1's pick.
__launch_bounds__(256)
__global__ void vq_resolve3(const float* __restrict__ z,
                            const float* __restrict__ cb,
                            const double* __restrict__ cbn64,
                            float* __restrict__ out_zq,
                            float* __restrict__ out_idx,
                            const int* __restrict__ cnt,
                            const int* __restrict__ listA, int capA,
                            const float* __restrict__ zws, int zcap) {
  const int lane = threadIdx.x & 63;
  const int wid = (blockIdx.x * blockDim.x + threadIdx.x) >> 6;
  const int nw = (gridDim.x * blockDim.x) >> 6;
  int n = cnt[0];
  if (n > capA) n = capA;

  for (int i = wid; i < n; i += nw) {
    const int e0 = listA[2 * i];
    const int e1 = listA[2 * i + 1];
    const int p = e0 & 0xFFFF;
    int cand[3];
    cand[0] = (e0 >> 16) & 1023;
    cand[1] = e1 & 0xFFFF;
    cand[2] = (e1 >> 16) & 1023;
    const int b = p >> 12;
    const int hw = p & (HWSZ - 1);
    const int ch0 = lane * 4;

    double zv[4];
    if (i < zcap) {
      float4 zf = ((const float4*)(zws + (size_t)i * 256))[lane];
      zv[0] = (double)zf.x; zv[1] = (double)zf.y;
      zv[2] = (double)zf.z; zv[3] = (double)zf.w;
    } else {
      const float* zb = z + (size_t)b * (CDIM * HWSZ) + hw;
#pragma unroll
      for (int j = 0; j < 4; ++j) zv[j] = (double)zb[(size_t)(ch0 + j) * HWSZ];
    }

    double d[3];
#pragma unroll
    for (int tt = 0; tt < 3; ++tt) {
      float4 cv = *(const float4*)(cb + (size_t)cand[tt] * CDIM + ch0);
      double s = zv[0] * (double)cv.x;
      s = fma(zv[1], (double)cv.y, s);
      s = fma(zv[2], (double)cv.z, s);
      s = fma(zv[3], (double)cv.w, s);
#pragma unroll
      for (int off = 32; off; off >>= 1) s += __shfl_xor(s, off, 64);
      d[tt] = fma(-2.0, s, cbn64[cand[tt]]);
    }

    double bd = d[0];
    int bi = cand[0];
#pragma unroll
    for (int tt = 1; tt < 3; ++tt) {
      bool takes = (d[tt] < bd) || (d[tt] == bd && cand[tt] < bi);
      bd = takes ? d[tt] : bd;
      bi = takes ? cand[tt] : bi;
    }

    if (bi != cand[0]) {
      if (lane == 0) out_idx[p] = (float)bi;
      float4 cv = *(const float4*)(cb + (size_t)bi * CDIM + ch0);
      float* ob = out_zq + (size_t)b * (CDIM * HWSZ) + hw;
      ob[(size_t)(ch0 + 0) * HWSZ] = cv.x;
      ob[(size_t)(ch0 + 1) * HWSZ] = cv.y;
      ob[(size_t)(ch0 + 2) * HWSZ] = cv.z;
      ob[(size_t)(ch0 + 3) * HWSZ] = cv.w;
    }
  }
}

// Fullscan: exact f64 full scan for triple-near-tie pixels. One block/pixel.
__launch_bounds__(256)
__global__ void vq_fullscan(const float* __restrict__ z,
                            const float* __restrict__ cb,
                            const double* __restrict__ cbn64,
                            float* __restrict__ out_zq,
                            float* __restrict__ out_idx,
                            const int* __restrict__ cnt,
                            const int* __restrict__ listB, int capB) {
  __shared__ double zl[256];
  __shared__ double sd[4];
  __shared__ int si[4];
  __shared__ int sfin;
  int n = cnt[1];
  if (n > capB) n = capB;
  const int t = threadIdx.x;
  const int w = t >> 6;
  const int lane = t & 63;

  for (int i = blockIdx.x; i < n; i += gridDim.x) {
    const int p = listB[i];
    const int b = p >> 12;
    const int hw = p & (HWSZ - 1);
    const float* zb = z + (size_t)b * (CDIM * HWSZ) + hw;
    zl[t] = (double)zb[(size_t)t * HWSZ];
    __syncthreads();

    const int g = t >> 2;
    const int sub = t & 3;
    const double* zq4 = zl + sub * 64;
    double bd = 1e300;
    int bi = 0;

    for (int j = 0; j < 16; ++j) {
      const int code = g + 64 * j;
      const float* crow = cb + (size_t)code * CDIM + sub * 64;
      double s = 0.0;
#pragma unroll
      for (int q4 = 0; q4 < 64; q4 += 4) {
        float4 cv = *(const float4*)(crow + q4);
        s = fma(zq4[q4 + 0], (double)cv.x, s);
        s = fma(zq4[q4 + 1], (double)cv.y, s);
        s = fma(zq4[q4 + 2], (double)cv.z, s);
        s = fma(zq4[q4 + 3], (double)cv.w, s);
      }
      s += __shfl_xor(s, 1, 64);
      s += __shfl_xor(s, 2, 64);
      double d = fma(-2.0, s, cbn64[code]);
      bool takes = (d < bd) || (d == bd && code < bi);
      bd = takes ? d : bd;
      bi = takes ? code : bi;
    }

#pragma unroll
    for (int off = 4; off <= 32; off <<= 1) {
      double od = __shfl_xor(bd, off, 64);
      int oi = __shfl_xor(bi, off, 64);
      bool takes = (od < bd) || (od == bd && oi < bi);
      bd = takes ? od : bd;
      bi = takes ? oi : bi;
    }
    if (lane == 0) { sd[w] = bd; si[w] = bi; }
    __syncthreads();
    if (t == 0) {
      double fd = sd[0];
      int fi = si[0];
#pragma unroll
      for (int k = 1; k < 4; ++k) {
        bool takes = (sd[k] < fd) || (sd[k] == fd && si[k] < fi);
        fd = takes ? sd[k] : fd;
        fi = takes ? si[k] : fi;
      }
      const int old = (int)out_idx[p];
      sfin = (fi != old) ? fi : -1;
      if (fi != old) out_idx[p] = (float)fi;
    }
    __syncthreads();
    const int best = sfin;
    if (best >= 0) {
      float* ob = out_zq + (size_t)b * (CDIM * HWSZ) + hw;
      ob[(size_t)t * HWSZ] = cb[(size_t)best * CDIM + t];
    }
    __syncthreads();
  }
}

extern "C" void kernel_launch(void* const* d_in, const int* in_sizes, int n_in,
                              void* d_out, int out_size, void* d_ws, size_t ws_size,
                              hipStream_t stream) {
  const float* z = (const float*)d_in[0];
  const float* cb = (const float*)d_in[1];
  float* out = (float*)d_out;
  float* out_zq = out;
  float* out_idx = out + ZQ_ELEMS;

  char* ws = (char*)d_ws;
  unsigned short* cbswz = (unsigned short*)(ws + WS_CBSWZ);
  double* cbn64 = (double*)(ws + WS_CBN64);
  float* cbn32p = (float*)(ws + WS_CBN32);
  int* cnt = (int*)(ws + WS_CNT);

  long long avail = (long long)ws_size - WS_LISTS;
  if (avail < 0) avail = 0;
  long long capA_ll = (avail / 4) / 8;          // listA <= 1/4 of avail
  if (capA_ll > NPIX) capA_ll = NPIX;
  int capA = (int)capA_ll;
  int* listA = (int*)(ws + WS_LISTS);
  long long rem = avail - (long long)capA * 8;
  long long capB_ll = rem / 8;                  // listB <= 1/2 of remainder
  if (capB_ll > NPIX) capB_ll = NPIX;
  if (capB_ll < 0) capB_ll = 0;
  int capB = (int)capB_ll;
  int* listB = (int*)(ws + WS_LISTS + (size_t)capA * 8);
  long long zoff = (WS_LISTS + (long long)capA * 8 + (long long)capB * 4 + 15) &
                   ~15LL;
  long long zcap_ll = ((long long)ws_size - zoff) / 1024;
  if (zcap_ll < 0) zcap_ll = 0;
  if (zcap_ll > capA) zcap_ll = capA;
  int zcap = (int)zcap_ll;
  float* zws = (float*)(ws + zoff);

  vq_prep<<<256, 256, 0, stream>>>(cb, cbswz, cbn64, cbn32p, cnt);
  vq_stage1<<<1024, 256, 53248, stream>>>(z, cb, cbswz, cbn32p, out_zq, out_idx,
                                          cnt, listA, capA, listB, capB,
                                          zws, zcap);
  vq_resolve3<<<1024, 256, 0, stream>>>(z, cb, cbn64, out_zq, out_idx,
                                        cnt, listA, capA, zws, zcap);
  vq_fullscan<<<256, 256, 0, stream>>>(z, cb, cbn64, out_zq, out_idx,
                                       cnt, listB, capB);
}

// Round 9
// 150.618 us; speedup vs baseline: 2.1080x; 1.0328x over previous
//
#include <hip/hip_runtime.h>

// PixelVectorQuantizer: z [16,256,64,64] f32, codebook [1024,256] f32
// outputs: zq (f32) + indices (as f32 values), concatenated in d_out.
//
// prep:     codebook -> (-2*c) bf16 in FRAGMENT-STREAM order
//           [chunk16][kk][code][lg] + f64 norms + biased f32 norms.
// stage1:   bf16 MFMA distance GEMM, 64 px/wave x 512 codes (code-split),
//           norm folded into MFMA C-init, cvt_pk bf16 conversion,
//           triple-buffered LDS chunks + counted vmcnt(4) + raw s_barrier.
//           u32 sort-keys, v_med3_u32 top-3; cross-wave merge.
// resolve3: exact f64 check of 3 candidates (z from staged rows).
// fullscan: exact f64 full scan for triple-near-ties.

#define HWSZ 4096
#define CDIM 256
#define KCODES 1024
#define NPIX 65536
#define ZQ_ELEMS (16 * 256 * 4096)
#define MARGIN 0.75f

// ws layout (fixed part)
#define WS_CBSWZ 0          // 64 chunks x 8 KB fragment-stream = 524288 B
#define WS_CBN64 524288     // double[1024]
#define WS_CBN32 532480     // float[1024]  (= ||c||^2 + 512)
#define WS_CNT   536576     // int cntA, int cntB
#define WS_LISTS 536592     // listA (8B) | listB (4B) | zws (1KB rows)

// LDS layout (stage1)
#define L_BUF0   0          // 3 x 16 KB chunk buffers
#define L_NRM    49152      // float[1024]
#define L_MK     53248      // u32[128][2][3] = 3072
#define L_SBEST  56320      // int[128]
#define L_FLP    56832      // int[128]
#define L_FLQ    57344      // int[128]
#define L_LCNT   57856      // int
#define L_TOTAL  58368

typedef __attribute__((ext_vector_type(8))) short bf16x8;
typedef __attribute__((ext_vector_type(4))) float f32x4;
typedef __attribute__((ext_vector_type(4))) unsigned short us4;

#define MFMA16(a, b, c) __builtin_amdgcn_mfma_f32_16x16x32_bf16(a, b, c, 0, 0, 0)

__device__ __forceinline__ unsigned short f2bf(float f) {
  unsigned u = __float_as_uint(f);
  unsigned r = u + 0x7FFFu + ((u >> 16) & 1u);   // RNE
  return (unsigned short)(r >> 16);
}

// pack two f32 -> two bf16 (RNE), one instruction
__device__ __forceinline__ unsigned cvtpk(float lo, float hi) {
  unsigned r;
  asm("v_cvt_pk_bf16_f32 %0, %1, %2" : "=v"(r) : "v"(lo), "v"(hi));
  return r;
}

__device__ __forceinline__ void gload_lds16(const void* g, void* l) {
  __builtin_amdgcn_global_load_lds(
      (const __attribute__((address_space(1))) unsigned int*)g,
      (__attribute__((address_space(3))) unsigned int*)l, 16, 0, 0);
}

// 3-op sorted-triple insert on u32 keys: min + 2x v_med3_u32.
__device__ __forceinline__ void ins3(unsigned& k1, unsigned& k2, unsigned& k3,
                                     unsigned k) {
  unsigned nk2, nk3;
  asm("v_med3_u32 %0, %1, %2, %3" : "=v"(nk2) : "v"(k1), "v"(k2), "v"(k));
  asm("v_med3_u32 %0, %1, %2, %3" : "=v"(nk3) : "v"(k2), "v"(k3), "v"(k));
  k1 = k1 < k ? k1 : k;
  k2 = nk2;
  k3 = nk3;
}

__device__ __forceinline__ float keyf(unsigned k) {
  return __uint_as_float(k & 0xFFFFFC00u);
}

// Fused prep: 256 blocks x 256 thr; block b -> codes 4b..4b+3 (wave/code).
// Stream layout: chunk K = (code>>9)*32 + ((code>>4)&31) holds 16 codes;
// byte offset = kk*1024 + (code&15)*64 + lg*16 + (ch&7)*2.
__global__ void vq_prep(const float* __restrict__ cb,
                        unsigned short* __restrict__ cbswz,
                        double* __restrict__ cbn64,
                        float* __restrict__ cbn32p,
                        int* __restrict__ cnt) {
  const int t = threadIdx.x;
  if (blockIdx.x == 0 && t == 0) { cnt[0] = 0; cnt[1] = 0; }
  const int code = blockIdx.x * 4 + (t >> 6);
  const int lane = t & 63;
  const int c4 = lane * 4;

  float4 v = *(const float4*)(cb + (size_t)code * CDIM + c4);
  us4 hv;  // store -2*c (exact power-of-2 scale) so MFMA yields -2 z.c
  hv.x = f2bf(-2.f * v.x); hv.y = f2bf(-2.f * v.y);
  hv.z = f2bf(-2.f * v.z); hv.w = f2bf(-2.f * v.w);
  const int K = (code >> 9) * 32 + ((code >> 4) & 31);
  const int kk = c4 >> 5;
  const int lg = (c4 >> 3) & 3;
  const int within = (c4 & 7) * 2;
  size_t off = (size_t)K * 8192 + kk * 1024 + (code & 15) * 64 + lg * 16 + within;
  *(us4*)((char*)cbswz + off) = hv;

  double s = (double)v.x * v.x;
  s = fma((double)v.y, (double)v.y, s);
  s = fma((double)v.z, (double)v.z, s);
  s = fma((double)v.w, (double)v.w, s);
#pragma unroll
  for (int o = 32; o; o >>= 1) s += __shfl_xor(s, o, 64);
  if (lane == 0) {
    cbn64[code] = s;
    cbn32p[code] = (float)s + 512.0f;  // bias keeps keys positive
  }
}

// Stage 1: 512 blocks x 256 thr (4 waves), 128 px/block.
// wave w: px-half h=w>>1 (64 px), code-half q=w&1 (512 codes).
__launch_bounds__(256, 2)
__global__ void vq_stage1(const float* __restrict__ z,
                          const float* __restrict__ cb,
                          const unsigned short* __restrict__ cbswz,
                          const float* __restrict__ cbn32p,
                          float* __restrict__ out_zq,
                          float* __restrict__ out_idx,
                          int* __restrict__ cnt,      // [cntA, cntB]
                          int* __restrict__ listA, int capA,
                          int* __restrict__ listB, int capB,
                          float* __restrict__ zws, int zcap) {
  extern __shared__ char smem[];
  const int t = threadIdx.x;
  const int w = t >> 6;
  const int lane = t & 63;
  const int lg = lane >> 4;
  const int lcode = lane & 15;
  const int h = w >> 1;   // px half
  const int q = w & 1;    // code half
  const int p0 = blockIdx.x * 128;
  const int b = p0 >> 12;
  const int hw0 = p0 & (HWSZ - 1);
  const float* zb = z + (size_t)b * (CDIM * HWSZ) + hw0;

  char* const bb0 = smem + q * 8192;
  char* const bb1 = smem + 16384 + q * 8192;
  char* const bb2 = smem + 32768 + q * 8192;
  float* nrm = (float*)(smem + L_NRM);

  const int stl = h * 4096 + lane * 16;
  const char* cbbase = (const char*)cbswz + (size_t)q * 262144 + stl;

#define STAGE(CIDX, SBUF)                                             \
  {                                                                   \
    const char* gs_ = cbbase + ((size_t)(CIDX) << 13);                \
    char* ld_ = (SBUF) + stl;                                         \
    gload_lds16(gs_, ld_);                                            \
    gload_lds16(gs_ + 1024, ld_ + 1024);                              \
    gload_lds16(gs_ + 2048, ld_ + 2048);                              \
    gload_lds16(gs_ + 3072, ld_ + 3072);                              \
  }

  // ---- prologue: stage chunks 0,1 ----
  STAGE(0, bb0);
  STAGE(1, bb1);

  // ---- A fragments: 64 px x 256 ch per wave, direct global -> regs ----
  bf16x8 af[4][8];
#pragma unroll
  for (int T = 0; T < 4; ++T) {
    const float* zr = zb + (h * 64 + T * 16 + lcode);
#pragma unroll
    for (int kk = 0; kk < 8; ++kk) {
      const int ch0 = kk * 32 + lg * 8;
      float v0 = zr[(size_t)(ch0 + 0) * HWSZ];
      float v1 = zr[(size_t)(ch0 + 1) * HWSZ];
      float v2 = zr[(size_t)(ch0 + 2) * HWSZ];
      float v3 = zr[(size_t)(ch0 + 3) * HWSZ];
      float v4 = zr[(size_t)(ch0 + 4) * HWSZ];
      float v5 = zr[(size_t)(ch0 + 5) * HWSZ];
      float v6 = zr[(size_t)(ch0 + 6) * HWSZ];
      float v7 = zr[(size_t)(ch0 + 7) * HWSZ];
      unsigned p01 = cvtpk(v0, v1);
      unsigned p23 = cvtpk(v2, v3);
      unsigned p45 = cvtpk(v4, v5);
      unsigned p67 = cvtpk(v6, v7);
      bf16x8 f;
      f[0] = (short)(p01 & 0xFFFF); f[1] = (short)(p01 >> 16);
      f[2] = (short)(p23 & 0xFFFF); f[3] = (short)(p23 >> 16);
      f[4] = (short)(p45 & 0xFFFF); f[5] = (short)(p45 >> 16);
      f[6] = (short)(p67 & 0xFFFF); f[7] = (short)(p67 >> 16);
      af[T][kk] = f;
    }
  }

  // ---- norm table -> LDS ----
  *(float4*)(nrm + t * 4) = *(const float4*)(cbn32p + t * 4);
  __syncthreads();   // full drain ONCE

  unsigned k1[4][4], k2[4][4], k3[4][4];
#pragma unroll
  for (int T = 0; T < 4; ++T)
#pragma unroll
    for (int q4 = 0; q4 < 4; ++q4) {
      k1[T][q4] = 0xFFFFFFFFu; k2[T][q4] = 0xFFFFFFFFu; k3[T][q4] = 0xFFFFFFFFu;
    }

  const int bq = lcode * 64 + lg * 16;          // B-frag lane offset
  const float* nrmp = nrm + q * 512 + lcode;    // per-lane norm pointer
  const int kbase = q * 512 + lcode;
  float cnn = nrmp[0];                          // prefetched chunk-0 norm

#define BODY(CIDX, RBUF, SBUF, DOSTAGE, WN)                           \
  {                                                                   \
    asm volatile("s_waitcnt vmcnt(" WN ")" ::: "memory");             \
    __builtin_amdgcn_s_barrier();                                     \
    __builtin_amdgcn_sched_barrier(0);                                \
    const float cn_ = cnn;                                            \
    if ((CIDX) < 31) cnn = nrmp[((CIDX) + 1) * 16];                   \
    if (DOSTAGE) STAGE((CIDX) + 2, SBUF);                             \
    const char* pb_ = (RBUF) + bq;                                    \
    f32x4 a0 = {cn_, cn_, cn_, cn_};                                  \
    f32x4 a1 = {cn_, cn_, cn_, cn_};                                  \
    f32x4 a2 = {cn_, cn_, cn_, cn_};                                  \
    f32x4 a3 = {cn_, cn_, cn_, cn_};                                  \
    _Pragma("unroll")                                                 \
    for (int kk = 0; kk < 8; ++kk) {                                  \
      bf16x8 bf_ = *(const bf16x8*)(pb_ + kk * 1024);                 \
      a0 = MFMA16(af[0][kk], bf_, a0);                                \
      a1 = MFMA16(af[1][kk], bf_, a1);                                \
      a2 = MFMA16(af[2][kk], bf_, a2);                                \
      a3 = MFMA16(af[3][kk], bf_, a3);                                \
    }                                                                 \
    const unsigned code_ = (unsigned)(kbase + (CIDX) * 16);           \
    _Pragma("unroll")                                                 \
    for (int q4 = 0; q4 < 4; ++q4) {                                  \
      ins3(k1[0][q4], k2[0][q4], k3[0][q4],                           \
           (__float_as_uint(a0[q4]) & 0xFFFFFC00u) | code_);          \
      ins3(k1[1][q4], k2[1][q4], k3[1][q4],                           \
           (__float_as_uint(a1[q4]) & 0xFFFFFC00u) | code_);          \
      ins3(k1[2][q4], k2[2][q4], k3[2][q4],                           \
           (__float_as_uint(a2[q4]) & 0xFFFFFC00u) | code_);          \
      ins3(k1[3][q4], k2[3][q4], k3[3][q4],                           \
           (__float_as_uint(a3[q4]) & 0xFFFFFC00u) | code_);          \
    }                                                                 \
  }

#pragma unroll 1
  for (int c3 = 0; c3 < 30; c3 += 3) {
    BODY(c3 + 0, bb0, bb2, 1, "4");
    BODY(c3 + 1, bb1, bb0, 1, "4");
    BODY(c3 + 2, bb2, bb1, 1, "4");
  }
  BODY(30, bb0, bb2, 0, "4");
  BODY(31, bb1, bb0, 0, "0");
#undef BODY
#undef STAGE

  // ---- cross-lane top-3 merge over the 16-column group ----
#pragma unroll
  for (int mask = 1; mask <= 8; mask <<= 1) {
#pragma unroll
    for (int T = 0; T < 4; ++T)
#pragma unroll
      for (int q4 = 0; q4 < 4; ++q4) {
        unsigned o1 = __shfl_xor(k1[T][q4], mask, 64);
        unsigned o2 = __shfl_xor(k2[T][q4], mask, 64);
        unsigned o3 = __shfl_xor(k3[T][q4], mask, 64);
        ins3(k1[T][q4], k2[T][q4], k3[T][q4], o1);
        ins3(k1[T][q4], k2[T][q4], k3[T][q4], o2);
        ins3(k1[T][q4], k2[T][q4], k3[T][q4], o3);
      }
  }

  // ---- cross-wave merge (code halves) via scratch LDS ----
  unsigned* mk = (unsigned*)(smem + L_MK);   // [128 px][2 half][3]
  int* sbest = (int*)(smem + L_SBEST);
  int* flp = (int*)(smem + L_FLP);
  int* flq = (int*)(smem + L_FLQ);
  int* lcnt = (int*)(smem + L_LCNT);
  if (t == 0) *lcnt = 0;
  if (lcode == 0) {
#pragma unroll
    for (int T = 0; T < 4; ++T)
#pragma unroll
      for (int q4 = 0; q4 < 4; ++q4) {
        int row = h * 64 + T * 16 + lg * 4 + q4;
        unsigned* d = mk + (row * 2 + q) * 3;
        d[0] = k1[T][q4]; d[1] = k2[T][q4]; d[2] = k3[T][q4];
      }
  }
  __syncthreads();

  if (t < 128) {
    unsigned a1 = mk[t * 6 + 0], a2 = mk[t * 6 + 1], a3 = mk[t * 6 + 2];
    ins3(a1, a2, a3, mk[t * 6 + 3]);
    ins3(a1, a2, a3, mk[t * 6 + 4]);
    ins3(a1, a2, a3, mk[t * 6 + 5]);
    const int p = p0 + t;
    const int i1 = (int)(a1 & 1023u);
    sbest[t] = i1;
    out_idx[p] = (float)i1;
    float f1 = keyf(a1);
    float g2 = keyf(a2) - f1;
    float g3 = keyf(a3) - f1;
    if (g3 < MARGIN) {
      int pos = atomicAdd(cnt + 1, 1);
      if (pos < capB) listB[pos] = p;
    } else if (g2 < MARGIN) {
      int pos = atomicAdd(cnt, 1);
      if (pos < capA) {
        listA[2 * pos] = p | (i1 << 16);
        listA[2 * pos + 1] = (int)(a2 & 1023u) | ((int)(a3 & 1023u) << 16);
        if (pos < zcap) {
          int li = atomicAdd(lcnt, 1);
          flp[li] = p;
          flq[li] = pos;
        }
      }
    }
  }
  __syncthreads();

  // ---- zq gather: coalesced over px ----
  {
    const int px = t & 127;
    const int best = sbest[px];
    const int ch0g = (t >> 7) * 128;
    const float* crow = cb + (size_t)best * CDIM + ch0g;
    float* ob = out_zq + (size_t)b * (CDIM * HWSZ) + (size_t)ch0g * HWSZ + hw0 + px;
#pragma unroll 4
    for (int c2 = 0; c2 < 128; c2 += 4) {
      float4 v = *(const float4*)(crow + c2);
      ob[(size_t)(c2 + 0) * HWSZ] = v.x;
      ob[(size_t)(c2 + 1) * HWSZ] = v.y;
      ob[(size_t)(c2 + 2) * HWSZ] = v.z;
      ob[(size_t)(c2 + 3) * HWSZ] = v.w;
    }
  }

  // ---- z-row dump for flagged px (lines are L2-hot from A loads) ----
  {
    const int nf = *lcnt;
    for (int e = 0; e < nf; ++e) {
      const int p = flp[e];
      const int slot = flq[e];
      const int bb = p >> 12;
      const int hh = p & (HWSZ - 1);
      zws[(size_t)slot * 256 + t] =
          z[(size_t)bb * (CDIM * HWSZ) + (size_t)t * HWSZ + hh];
    }
  }
}

// Resolve3: exact f64 check of the 3 candidate codes. One wave per entry.
// Writes only when the exact argmin differs from stage1's pick.
__launch_bounds__(256)
__global__ void vq_resolve3(const float* __restrict__ z,
                            const float* __restrict__ cb,
                            const double* __restrict__ cbn64,
                            float* __restrict__ out_zq,
                            float* __restrict__ out_idx,
                            const int* __restrict__ cnt,
                            const int* __restrict__ listA, int capA,
                            const float* __restrict__ zws, int zcap) {
  const int lane = threadIdx.x & 63;
  const int wid = (blockIdx.x * blockDim.x + threadIdx.x) >> 6;
  const int nw = (gridDim.x * blockDim.x) >> 6;
  int n = cnt[0];
  if (n > capA) n = capA;

  for (int i = wid; i < n; i += nw) {
    const int e0 = listA[2 * i];
    const int e1 = listA[2 * i + 1];
    const int p = e0 & 0xFFFF;
    int cand[3];
    cand[0] = (e0 >> 16) & 1023;
    cand[1] = e1 & 0xFFFF;
    cand[2] = (e1 >> 16) & 1023;
    const int b = p >> 12;
    const int hw = p & (HWSZ - 1);
    const int ch0 = lane * 4;

    double zv[4];
    if (i < zcap) {
      float4 zf = ((const float4*)(zws + (size_t)i * 256))[lane];
      zv[0] = (double)zf.x; zv[1] = (double)zf.y;
      zv[2] = (double)zf.z; zv[3] = (double)zf.w;
    } else {
      const float* zb = z + (size_t)b * (CDIM * HWSZ) + hw;
#pragma unroll
      for (int j = 0; j < 4; ++j) zv[j] = (double)zb[(size_t)(ch0 + j) * HWSZ];
    }

    double d[3];
#pragma unroll
    for (int tt = 0; tt < 3; ++tt) {
      float4 cv = *(const float4*)(cb + (size_t)cand[tt] * CDIM + ch0);
      double s = zv[0] * (double)cv.x;
      s = fma(zv[1], (double)cv.y, s);
      s = fma(zv[2], (double)cv.z, s);
      s = fma(zv[3], (double)cv.w, s);
#pragma unroll
      for (int off = 32; off; off >>= 1) s += __shfl_xor(s, off, 64);
      d[tt] = fma(-2.0, s, cbn64[cand[tt]]);
    }

    double bd = d[0];
    int bi = cand[0];
#pragma unroll
    for (int tt = 1; tt < 3; ++tt) {
      bool takes = (d[tt] < bd) || (d[tt] == bd && cand[tt] < bi);
      bd = takes ? d[tt] : bd;
      bi = takes ? cand[tt] : bi;
    }

    if (bi != cand[0]) {
      if (lane == 0) out_idx[p] = (float)bi;
      float4 cv = *(const float4*)(cb + (size_t)bi * CDIM + ch0);
      float* ob = out_zq + (size_t)b * (CDIM * HWSZ) + hw;
      ob[(size_t)(ch0 + 0) * HWSZ] = cv.x;
      ob[(size_t)(ch0 + 1) * HWSZ] = cv.y;
      ob[(size_t)(ch0 + 2) * HWSZ] = cv.z;
      ob[(size_t)(ch0 + 3) * HWSZ] = cv.w;
    }
  }
}

// Fullscan: exact f64 full scan for triple-near-tie pixels. One block/pixel.
__launch_bounds__(256)
__global__ void vq_fullscan(const float* __restrict__ z,
                            const float* __restrict__ cb,
                            const double* __restrict__ cbn64,
                            float* __restrict__ out_zq,
                            float* __restrict__ out_idx,
                            const int* __restrict__ cnt,
                            const int* __restrict__ listB, int capB) {
  __shared__ double zl[256];
  __shared__ double sd[4];
  __shared__ int si[4];
  __shared__ int sfin;
  int n = cnt[1];
  if (n > capB) n = capB;
  const int t = threadIdx.x;
  const int w = t >> 6;
  const int lane = t & 63;

  for (int i = blockIdx.x; i < n; i += gridDim.x) {
    const int p = listB[i];
    const int b = p >> 12;
    const int hw = p & (HWSZ - 1);
    const float* zb = z + (size_t)b * (CDIM * HWSZ) + hw;
    zl[t] = (double)zb[(size_t)t * HWSZ];
    __syncthreads();

    const int g = t >> 2;
    const int sub = t & 3;
    const double* zq4 = zl + sub * 64;
    double bd = 1e300;
    int bi = 0;

    for (int j = 0; j < 16; ++j) {
      const int code = g + 64 * j;
      const float* crow = cb + (size_t)code * CDIM + sub * 64;
      double s = 0.0;
#pragma unroll
      for (int q4 = 0; q4 < 64; q4 += 4) {
        float4 cv = *(const float4*)(crow + q4);
        s = fma(zq4[q4 + 0], (double)cv.x, s);
        s = fma(zq4[q4 + 1], (double)cv.y, s);
        s = fma(zq4[q4 + 2], (double)cv.z, s);
        s = fma(zq4[q4 + 3], (double)cv.w, s);
      }
      s += __shfl_xor(s, 1, 64);
      s += __shfl_xor(s, 2, 64);
      double d = fma(-2.0, s, cbn64[code]);
      bool takes = (d < bd) || (d == bd && code < bi);
      bd = takes ? d : bd;
      bi = takes ? code : bi;
    }

#pragma unroll
    for (int off = 4; off <= 32; off <<= 1) {
      double od = __shfl_xor(bd, off, 64);
      int oi = __shfl_xor(bi, off, 64);
      bool takes = (od < bd) || (od == bd && oi < bi);
      bd = takes ? od : bd;
      bi = takes ? oi : bi;
    }
    if (lane == 0) { sd[w] = bd; si[w] = bi; }
    __syncthreads();
    if (t == 0) {
      double fd = sd[0];
      int fi = si[0];
#pragma unroll
      for (int k = 1; k < 4; ++k) {
        bool takes = (sd[k] < fd) || (sd[k] == fd && si[k] < fi);
        fd = takes ? sd[k] : fd;
        fi = takes ? si[k] : fi;
      }
      const int old = (int)out_idx[p];
      sfin = (fi != old) ? fi : -1;
      if (fi != old) out_idx[p] = (float)fi;
    }
    __syncthreads();
    const int best = sfin;
    if (best >= 0) {
      float* ob = out_zq + (size_t)b * (CDIM * HWSZ) + hw;
      ob[(size_t)t * HWSZ] = cb[(size_t)best * CDIM + t];
    }
    __syncthreads();
  }
}

extern "C" void kernel_launch(void* const* d_in, const int* in_sizes, int n_in,
                              void* d_out, int out_size, void* d_ws, size_t ws_size,
                              hipStream_t stream) {
  const float* z = (const float*)d_in[0];
  const float* cb = (const float*)d_in[1];
  float* out = (float*)d_out;
  float* out_zq = out;
  float* out_idx = out + ZQ_ELEMS;

  char* ws = (char*)d_ws;
  unsigned short* cbswz = (unsigned short*)(ws + WS_CBSWZ);
  double* cbn64 = (double*)(ws + WS_CBN64);
  float* cbn32p = (float*)(ws + WS_CBN32);
  int* cnt = (int*)(ws + WS_CNT);

  long long avail = (long long)ws_size - WS_LISTS;
  if (avail < 0) avail = 0;
  long long capA_ll = (avail / 4) / 8;          // listA <= 1/4 of avail
  if (capA_ll > NPIX) capA_ll = NPIX;
  int capA = (int)capA_ll;
  int* listA = (int*)(ws + WS_LISTS);
  long long rem = avail - (long long)capA * 8;
  long long capB_ll = rem / 8;                  // listB <= 1/2 of remainder
  if (capB_ll > NPIX) capB_ll = NPIX;
  if (capB_ll < 0) capB_ll = 0;
  int capB = (int)capB_ll;
  int* listB = (int*)(ws + WS_LISTS + (size_t)capA * 8);
  long long zoff = (WS_LISTS + (long long)capA * 8 + (long long)capB * 4 + 15) &
                   ~15LL;
  long long zcap_ll = ((long long)ws_size - zoff) / 1024;
  if (zcap_ll < 0) zcap_ll = 0;
  if (zcap_ll > capA) zcap_ll = capA;
  int zcap = (int)zcap_ll;
  float* zws = (float*)(ws + zoff);

  vq_prep<<<256, 256, 0, stream>>>(cb, cbswz, cbn64, cbn32p, cnt);
  vq_stage1<<<512, 256, L_TOTAL, stream>>>(z, cb, cbswz, cbn32p, out_zq, out_idx,
                                           cnt, listA, capA, listB, capB,
                                           zws, zcap);
  vq_resolve3<<<1024, 256, 0, stream>>>(z, cb, cbn64, out_zq, out_idx,
                                        cnt, listA, capA, zws, zcap);
  vq_fullscan<<<256, 256, 0, stream>>>(z, cb, cbn64, out_zq, out_idx,
                                       cnt, listB, capB);
}